// Round 5
// baseline (228.529 us; speedup 1.0000x reference)
//
#include <hip/hip_runtime.h>
#include <hip/hip_bf16.h>
#include <stdint.h>

// ---------------------------------------------------------------------------
// TensorNet: fused encoder MLP (128->256->256->256, relu) over 32x4096 tokens,
// per-batch mean -> p = relu(m^2) -> decoder MLP (256->512->512->10).
// Inputs/outputs fp32. Encoder via bf16 MFMA (A=weights M=hidden, B=act
// N=tokens) + fp32 accum.
// R4: encoder 66us, MfmaUtil 25%, 5.77M LDS conflicts (3M from the LDS
// scratch token-reduction, 16-way), 7 barriers/block.
// R5: (a) layer-1 B-frags straight from global x (32 contiguous bytes/lane;
// L1-broadcast across waves) — kills x staging + 2 barriers; (b) token
// reduction via __shfl_xor butterfly in the l15 subgroup — kills the 16-way
// conflict loop + 2 barriers. 3 barriers/block remain.
// ---------------------------------------------------------------------------

#define NIN   128
#define NHID  256
#define NDEC  512
#define NOUTC 10
#define BATCH 32
#define NTOK  4096
#define MTILE 64
#define TPB   64               // encoder blocks per batch (4096/64)
#define NBLK  (BATCH * TPB)    // 2048 encoder blocks
#define HPAD  264              // h-tile LDS row stride (bf16 elems), 528B rows

typedef short bf16x8 __attribute__((ext_vector_type(8)));
typedef float floatx4 __attribute__((ext_vector_type(4)));

__device__ __forceinline__ uint16_t f2b(float f) {
  union { float f; uint32_t u; } v; v.f = f;
  uint32_t r = v.u + 0x7FFFu + ((v.u >> 16) & 1u);   // RNE
  return (uint16_t)(r >> 16);
}
__device__ __forceinline__ uint32_t pkbf(float lo, float hi) {
  __hip_bfloat162 h = __float22bfloat162_rn(float2{lo, hi});  // v_cvt_pk_bf16_f32
  union { __hip_bfloat162 h; uint32_t u; } c; c.h = h;
  return c.u;
}

// ---------------------------------------------------------------------------
// Pack W1/W2/W3 (fp32 [K][256] row-major) into bf16 MFMA-fragment order:
//   packed[((mt*KC + kc)*64 + lane)*8 + j] =
//       bf16( W[kc*32 + (lane>>4)*8 + j][mt*16 + (lane&15)] )
// Serves as the encoder's A-operand (A[m][k] = W[k][m], m=hidden out).
// Also zero-inits the msum accumulator (poisoned 0xAA by the harness).
// ---------------------------------------------------------------------------
__global__ __launch_bounds__(256) void pack_weights(
    const float* __restrict__ W1, const float* __restrict__ W2,
    const float* __restrict__ W3, uint16_t* __restrict__ out,
    float* __restrict__ msum) {
  int p = blockIdx.x * blockDim.x + threadIdx.x;
  if (p < BATCH * NHID) msum[p] = 0.f;
  const float* W; int K; int base;
  if (p < 32768)      { W = W1; K = NIN;  base = 0; }
  else if (p < 98304) { W = W2; K = NHID; base = 32768; p -= 32768; }
  else                { W = W3; K = NHID; base = 98304; p -= 98304; }
  int j    = p & 7;
  int lane = (p >> 3) & 63;
  int rest = p >> 9;
  int KC = K >> 5;               // K/32 k-chunks
  int kc = rest % KC;
  int mt = rest / KC;
  int m = mt * 16 + (lane & 15);
  int k = kc * 32 + ((lane >> 4) << 3) + j;
  out[base + (((mt * KC + kc) * 64 + lane) << 3) + j] = f2b(W[k * NHID + m]);
}

// ---------------------------------------------------------------------------
// Fused encoder. Block = 256 thr (4 waves), 64 tokens. Wave w owns hidden
// rows [64w, 64w+64) (A = packed weights); token tiles shared (B). D tile:
// lane holds j = 64w+jt*16+q*4+r (contiguous run) at token t = tt*16+l15.
// ---------------------------------------------------------------------------
__global__ __launch_bounds__(256, 4) void encoder(
    const float* __restrict__ x,        // [BATCH*NTOK][NIN] fp32
    const uint16_t* __restrict__ pW,    // packed bf16 weights
    const float* __restrict__ b1,
    const float* __restrict__ b2,
    const float* __restrict__ b3,
    float* __restrict__ msum) {         // [BATCH][NHID] fp32 accum
  __shared__ uint16_t Hs[MTILE * HPAD]; // 33792 B (h1/h2, rows = tokens)

  const int tid  = threadIdx.x;
  const int wave = tid >> 6;
  const int lane = tid & 63;
  const int l15  = lane & 15;
  const int q    = lane >> 4;
  const int tok0 = blockIdx.x * MTILE;

  const uint16_t* pW1 = pW;             // KC=4
  const uint16_t* pW2 = pW + 32768;     // KC=8
  const uint16_t* pW3 = pW + 98304;     // KC=8

  floatx4 acc[4][4];   // [jt][tt]

  // ---------------- layer 1: K = 128, A = W1^T, B = x (direct global) ------
  for (int jt = 0; jt < 4; ++jt)
    for (int tt = 0; tt < 4; ++tt)
      acc[jt][tt] = (floatx4){0.f, 0.f, 0.f, 0.f};
  {
    // lane's base: token tok0 + l15, k-offset q*8
    const float* xb = x + (size_t)(tok0 + l15) * NIN + q * 8;
#pragma unroll
    for (int kc = 0; kc < 4; ++kc) {
      bf16x8 a[4], b[4];
#pragma unroll
      for (int jt = 0; jt < 4; ++jt)
        a[jt] = *(const bf16x8*)(pW1 + ((((wave * 4 + jt) * 4 + kc) * 64 + lane) << 3));
#pragma unroll
      for (int tt = 0; tt < 4; ++tt) {
        const float* xp = xb + tt * 16 * NIN + kc * 32;
        float4 va = *(const float4*)xp;
        float4 vb = *(const float4*)(xp + 4);
        union { bf16x8 v; uint32_t u[4]; } bbv;
        bbv.u[0] = pkbf(va.x, va.y);
        bbv.u[1] = pkbf(va.z, va.w);
        bbv.u[2] = pkbf(vb.x, vb.y);
        bbv.u[3] = pkbf(vb.z, vb.w);
        b[tt] = bbv.v;
      }
#pragma unroll
      for (int jt = 0; jt < 4; ++jt)
#pragma unroll
        for (int tt = 0; tt < 4; ++tt)
          acc[jt][tt] = __builtin_amdgcn_mfma_f32_16x16x32_bf16(
              a[jt], b[tt], acc[jt][tt], 0, 0, 0);
    }
  }
  // bias + relu -> Hs (h1), rows = tokens, stride HPAD
#pragma unroll
  for (int jt = 0; jt < 4; ++jt) {
    const int jbase = wave * 64 + jt * 16 + q * 4;
    const float4 bb = *(const float4*)&b1[jbase];
#pragma unroll
    for (int tt = 0; tt < 4; ++tt) {
      const int t = tt * 16 + l15;
      float v0 = fmaxf(acc[jt][tt][0] + bb.x, 0.f);
      float v1 = fmaxf(acc[jt][tt][1] + bb.y, 0.f);
      float v2 = fmaxf(acc[jt][tt][2] + bb.z, 0.f);
      float v3 = fmaxf(acc[jt][tt][3] + bb.w, 0.f);
      *(uint2*)&Hs[t * HPAD + jbase] = make_uint2(pkbf(v0, v1), pkbf(v2, v3));
    }
  }
  __syncthreads();                       // barrier 1: h1 visible

  // ---------------- layer 2: K = 256, A = W2^T, B = h1 ----------------
  for (int jt = 0; jt < 4; ++jt)
    for (int tt = 0; tt < 4; ++tt)
      acc[jt][tt] = (floatx4){0.f, 0.f, 0.f, 0.f};
#pragma unroll
  for (int kc = 0; kc < 8; ++kc) {
    bf16x8 a[4], b[4];
#pragma unroll
    for (int jt = 0; jt < 4; ++jt)
      a[jt] = *(const bf16x8*)(pW2 + ((((wave * 4 + jt) * 8 + kc) * 64 + lane) << 3));
#pragma unroll
    for (int tt = 0; tt < 4; ++tt)
      b[tt] = *(const bf16x8*)&Hs[(tt * 16 + l15) * HPAD + kc * 32 + q * 8];
#pragma unroll
    for (int jt = 0; jt < 4; ++jt)
#pragma unroll
      for (int tt = 0; tt < 4; ++tt)
        acc[jt][tt] = __builtin_amdgcn_mfma_f32_16x16x32_bf16(
            a[jt], b[tt], acc[jt][tt], 0, 0, 0);
  }
  __syncthreads();                       // barrier 2: h1 reads done
#pragma unroll
  for (int jt = 0; jt < 4; ++jt) {
    const int jbase = wave * 64 + jt * 16 + q * 4;
    const float4 bb = *(const float4*)&b2[jbase];
#pragma unroll
    for (int tt = 0; tt < 4; ++tt) {
      const int t = tt * 16 + l15;
      float v0 = fmaxf(acc[jt][tt][0] + bb.x, 0.f);
      float v1 = fmaxf(acc[jt][tt][1] + bb.y, 0.f);
      float v2 = fmaxf(acc[jt][tt][2] + bb.z, 0.f);
      float v3 = fmaxf(acc[jt][tt][3] + bb.w, 0.f);
      *(uint2*)&Hs[t * HPAD + jbase] = make_uint2(pkbf(v0, v1), pkbf(v2, v3));
    }
  }
  __syncthreads();                       // barrier 3: h2 visible

  // ---------------- layer 3: K = 256, A = W3^T, B = h2, fused mean ---------
  for (int jt = 0; jt < 4; ++jt)
    for (int tt = 0; tt < 4; ++tt)
      acc[jt][tt] = (floatx4){0.f, 0.f, 0.f, 0.f};
#pragma unroll
  for (int kc = 0; kc < 8; ++kc) {
    bf16x8 a[4], b[4];
#pragma unroll
    for (int jt = 0; jt < 4; ++jt)
      a[jt] = *(const bf16x8*)(pW3 + ((((wave * 4 + jt) * 8 + kc) * 64 + lane) << 3));
#pragma unroll
    for (int tt = 0; tt < 4; ++tt)
      b[tt] = *(const bf16x8*)&Hs[(tt * 16 + l15) * HPAD + kc * 32 + q * 8];
#pragma unroll
    for (int jt = 0; jt < 4; ++jt)
#pragma unroll
      for (int tt = 0; tt < 4; ++tt)
        acc[jt][tt] = __builtin_amdgcn_mfma_f32_16x16x32_bf16(
            a[jt], b[tt], acc[jt][tt], 0, 0, 0);
  }

  // bias + relu + token-sum: local over 4 t-tiles, then butterfly over the
  // 16-lane l15 subgroup (masks 1,2,4,8 stay inside it); l15==0 lanes commit.
  const int batch = blockIdx.x >> 6;     // / TPB
#pragma unroll
  for (int jt = 0; jt < 4; ++jt) {
    const int jbase = wave * 64 + jt * 16 + q * 4;
    const float4 bb = *(const float4*)&b3[jbase];
    float s0 = 0.f, s1 = 0.f, s2 = 0.f, s3 = 0.f;
#pragma unroll
    for (int tt = 0; tt < 4; ++tt) {
      s0 += fmaxf(acc[jt][tt][0] + bb.x, 0.f);
      s1 += fmaxf(acc[jt][tt][1] + bb.y, 0.f);
      s2 += fmaxf(acc[jt][tt][2] + bb.z, 0.f);
      s3 += fmaxf(acc[jt][tt][3] + bb.w, 0.f);
    }
#pragma unroll
    for (int m = 1; m <= 8; m <<= 1) {
      s0 += __shfl_xor(s0, m, 64);
      s1 += __shfl_xor(s1, m, 64);
      s2 += __shfl_xor(s2, m, 64);
      s3 += __shfl_xor(s3, m, 64);
    }
    if (l15 == 0) {
      float* mp = &msum[batch * NHID + jbase];
      atomicAdd(mp + 0, s0);
      atomicAdd(mp + 1, s1);
      atomicAdd(mp + 2, s2);
      atomicAdd(mp + 3, s3);
    }
  }
}

// ---------------------------------------------------------------------------
// Decoder, split for parallelism (R2: monolithic = 32 blocks, 75us).
// ---------------------------------------------------------------------------
__global__ __launch_bounds__(256) void dec1_kernel(
    const float* __restrict__ msum, const float* __restrict__ D1,
    const float* __restrict__ c1, float* __restrict__ d1out) {
  __shared__ float p[NHID];
  __shared__ float red[256];
  const int b = blockIdx.y, jc = blockIdx.x, t = threadIdx.x;
  {
    float m = msum[b * NHID + t] * (1.f / NTOK);
    p[t] = m * m;                       // relu(m^2) == m^2
  }
  __syncthreads();
  const int j  = jc * 64 + (t & 63);
  const int kc = t >> 6;                // 0..3, 64 k's each
  float s = 0.f;
  for (int k = kc * 64; k < kc * 64 + 64; ++k)
    s += p[k] * D1[k * NDEC + j];
  red[t] = s;
  __syncthreads();
  if (t < 64) {
    float v = red[t] + red[64 + t] + red[128 + t] + red[192 + t]
            + c1[jc * 64 + t];
    d1out[b * NDEC + jc * 64 + t] = fmaxf(v, 0.f);
  }
}

__global__ __launch_bounds__(256) void dec2_kernel(
    const float* __restrict__ d1, const float* __restrict__ D2,
    const float* __restrict__ c2, float* __restrict__ d2out) {
  __shared__ float h[NDEC];
  __shared__ float red[256];
  const int b = blockIdx.y, jc = blockIdx.x, t = threadIdx.x;
  h[t]       = d1[b * NDEC + t];
  h[t + 256] = d1[b * NDEC + t + 256];
  __syncthreads();
  const int j  = jc * 64 + (t & 63);
  const int kc = t >> 6;                // 0..3, 128 k's each
  float s = 0.f;
  for (int k = kc * 128; k < kc * 128 + 128; ++k)
    s += h[k] * D2[k * NDEC + j];
  red[t] = s;
  __syncthreads();
  if (t < 64) {
    float v = red[t] + red[64 + t] + red[128 + t] + red[192 + t]
            + c2[jc * 64 + t];
    d2out[b * NDEC + jc * 64 + t] = fmaxf(v, 0.f);
  }
}

__global__ __launch_bounds__(256) void dec3_kernel(
    const float* __restrict__ d2, const float* __restrict__ D3,
    const float* __restrict__ c3, float* __restrict__ out) {
  __shared__ float h[NDEC];
  __shared__ float red[256];
  const int b = blockIdx.x, t = threadIdx.x;
  h[t]       = d2[b * NDEC + t];
  h[t + 256] = d2[b * NDEC + t + 256];
  __syncthreads();
  const int j  = t & 15;                // 16 slots, NOUTC=10 valid
  const int kc = t >> 4;                // 16 chunks x 32 k's
  float s = 0.f;
  if (j < NOUTC)
    for (int k = kc * 32; k < kc * 32 + 32; ++k)
      s += h[k] * D3[k * NOUTC + j];
  red[t] = s;
  __syncthreads();
  if (t < NOUTC) {
    float v = c3[t];
    for (int i = 0; i < 16; ++i) v += red[i * 16 + t];
    out[b * NOUTC + t] = v;
  }
}

// ---------------------------------------------------------------------------
extern "C" void kernel_launch(void* const* d_in, const int* in_sizes, int n_in,
                              void* d_out, int out_size, void* d_ws, size_t ws_size,
                              hipStream_t stream) {
  const float* x  = (const float*)d_in[0];
  const float* W1 = (const float*)d_in[1];
  const float* b1 = (const float*)d_in[2];
  const float* W2 = (const float*)d_in[3];
  const float* b2 = (const float*)d_in[4];
  const float* W3 = (const float*)d_in[5];
  const float* b3 = (const float*)d_in[6];
  const float* D1 = (const float*)d_in[7];
  const float* c1 = (const float*)d_in[8];
  const float* D2 = (const float*)d_in[9];
  const float* c2 = (const float*)d_in[10];
  const float* D3 = (const float*)d_in[11];
  const float* c3 = (const float*)d_in[12];

  // ws layout: [0,320K) packed bf16 W | [384K,416K) msum | [448K,512K) d1 |
  //            [512K,576K) d2
  uint16_t* pW   = (uint16_t*)d_ws;
  float*    msum = (float*)((char*)d_ws + 384 * 1024);
  float*    d1s  = (float*)((char*)d_ws + 448 * 1024);
  float*    d2s  = (float*)((char*)d_ws + 512 * 1024);

  pack_weights<<<640, 256, 0, stream>>>(W1, W2, W3, pW, msum);
  encoder<<<NBLK, 256, 0, stream>>>(x, pW, b1, b2, b3, msum);
  dec1_kernel<<<dim3(8, BATCH), 256, 0, stream>>>(msum, D1, c1, d1s);
  dec2_kernel<<<dim3(8, BATCH), 256, 0, stream>>>(d1s, D2, c2, d2s);
  dec3_kernel<<<BATCH, 256, 0, stream>>>(d2s, D3, c3, (float*)d_out);
}

// Round 6
// 227.748 us; speedup vs baseline: 1.0034x; 1.0034x over previous
//
#include <hip/hip_runtime.h>
#include <hip/hip_bf16.h>
#include <stdint.h>

// ---------------------------------------------------------------------------
// TensorNet: fused encoder MLP (128->256->256->256, relu) over 32x4096 tokens,
// per-batch mean -> p = relu(m^2) -> decoder MLP (256->512->512->10).
// Inputs/outputs fp32. Encoder via bf16 MFMA (A=weights M=hidden, B=act
// N=tokens) + fp32 accum.
// R5 FAILED: __launch_bounds__(256,4) forced VGPR=64 < the 64-reg acc array
// + frags -> scratch spills (WRITE_SIZE 2MB->22.5MB), MfmaUtil 25->18%.
// R6: revert to __launch_bounds__(256); keep R5's structural wins:
// (a) layer-1 B-frags straight from global x (32 contiguous bytes/lane,
// L1-broadcast across waves; no x staging, 2 fewer barriers); (b) token
// reduction via __shfl_xor butterfly (no 16-way-conflict LDS loop).
// ---------------------------------------------------------------------------

#define NIN   128
#define NHID  256
#define NDEC  512
#define NOUTC 10
#define BATCH 32
#define NTOK  4096
#define MTILE 64
#define TPB   64               // encoder blocks per batch (4096/64)
#define NBLK  (BATCH * TPB)    // 2048 encoder blocks
#define HPAD  264              // h-tile LDS row stride (bf16 elems), 528B rows

typedef short bf16x8 __attribute__((ext_vector_type(8)));
typedef float floatx4 __attribute__((ext_vector_type(4)));

__device__ __forceinline__ uint16_t f2b(float f) {
  union { float f; uint32_t u; } v; v.f = f;
  uint32_t r = v.u + 0x7FFFu + ((v.u >> 16) & 1u);   // RNE
  return (uint16_t)(r >> 16);
}
__device__ __forceinline__ uint32_t pkbf(float lo, float hi) {
  __hip_bfloat162 h = __float22bfloat162_rn(float2{lo, hi});  // v_cvt_pk_bf16_f32
  union { __hip_bfloat162 h; uint32_t u; } c; c.h = h;
  return c.u;
}

// ---------------------------------------------------------------------------
// Pack W1/W2/W3 (fp32 [K][256] row-major) into bf16 MFMA-fragment order:
//   packed[((mt*KC + kc)*64 + lane)*8 + j] =
//       bf16( W[kc*32 + (lane>>4)*8 + j][mt*16 + (lane&15)] )
// Serves as the encoder's A-operand (A[m][k] = W[k][m], m=hidden out).
// Also zero-inits the msum accumulator (poisoned 0xAA by the harness).
// ---------------------------------------------------------------------------
__global__ __launch_bounds__(256) void pack_weights(
    const float* __restrict__ W1, const float* __restrict__ W2,
    const float* __restrict__ W3, uint16_t* __restrict__ out,
    float* __restrict__ msum) {
  int p = blockIdx.x * blockDim.x + threadIdx.x;
  if (p < BATCH * NHID) msum[p] = 0.f;
  const float* W; int K; int base;
  if (p < 32768)      { W = W1; K = NIN;  base = 0; }
  else if (p < 98304) { W = W2; K = NHID; base = 32768; p -= 32768; }
  else                { W = W3; K = NHID; base = 98304; p -= 98304; }
  int j    = p & 7;
  int lane = (p >> 3) & 63;
  int rest = p >> 9;
  int KC = K >> 5;               // K/32 k-chunks
  int kc = rest % KC;
  int mt = rest / KC;
  int m = mt * 16 + (lane & 15);
  int k = kc * 32 + ((lane >> 4) << 3) + j;
  out[base + (((mt * KC + kc) * 64 + lane) << 3) + j] = f2b(W[k * NHID + m]);
}

// ---------------------------------------------------------------------------
// Fused encoder. Block = 256 thr (4 waves), 64 tokens. Wave w owns hidden
// rows [64w, 64w+64) (A = packed weights); token tiles shared (B). D tile:
// lane holds j = 64w+jt*16+q*4+r (contiguous run) at token t = tt*16+l15.
// NOTE: no min-waves launch bound — R5 showed (256,4) forces VGPR=64 and
// spills the 64-VGPR accumulator array to scratch (+20MB HBM writes).
// ---------------------------------------------------------------------------
__global__ __launch_bounds__(256) void encoder(
    const float* __restrict__ x,        // [BATCH*NTOK][NIN] fp32
    const uint16_t* __restrict__ pW,    // packed bf16 weights
    const float* __restrict__ b1,
    const float* __restrict__ b2,
    const float* __restrict__ b3,
    float* __restrict__ msum) {         // [BATCH][NHID] fp32 accum
  __shared__ uint16_t Hs[MTILE * HPAD]; // 33792 B (h1/h2, rows = tokens)

  const int tid  = threadIdx.x;
  const int wave = tid >> 6;
  const int lane = tid & 63;
  const int l15  = lane & 15;
  const int q    = lane >> 4;
  const int tok0 = blockIdx.x * MTILE;

  const uint16_t* pW1 = pW;             // KC=4
  const uint16_t* pW2 = pW + 32768;     // KC=8
  const uint16_t* pW3 = pW + 98304;     // KC=8

  floatx4 acc[4][4];   // [jt][tt]

  // ---------------- layer 1: K = 128, A = W1^T, B = x (direct global) ------
  for (int jt = 0; jt < 4; ++jt)
    for (int tt = 0; tt < 4; ++tt)
      acc[jt][tt] = (floatx4){0.f, 0.f, 0.f, 0.f};
  {
    // lane's base: token tok0 + l15, k-offset q*8
    const float* xb = x + (size_t)(tok0 + l15) * NIN + q * 8;
#pragma unroll
    for (int kc = 0; kc < 4; ++kc) {
      bf16x8 a[4], b[4];
#pragma unroll
      for (int jt = 0; jt < 4; ++jt)
        a[jt] = *(const bf16x8*)(pW1 + ((((wave * 4 + jt) * 4 + kc) * 64 + lane) << 3));
#pragma unroll
      for (int tt = 0; tt < 4; ++tt) {
        const float* xp = xb + tt * 16 * NIN + kc * 32;
        float4 va = *(const float4*)xp;
        float4 vb = *(const float4*)(xp + 4);
        union { bf16x8 v; uint32_t u[4]; } bbv;
        bbv.u[0] = pkbf(va.x, va.y);
        bbv.u[1] = pkbf(va.z, va.w);
        bbv.u[2] = pkbf(vb.x, vb.y);
        bbv.u[3] = pkbf(vb.z, vb.w);
        b[tt] = bbv.v;
      }
#pragma unroll
      for (int jt = 0; jt < 4; ++jt)
#pragma unroll
        for (int tt = 0; tt < 4; ++tt)
          acc[jt][tt] = __builtin_amdgcn_mfma_f32_16x16x32_bf16(
              a[jt], b[tt], acc[jt][tt], 0, 0, 0);
    }
  }
  // bias + relu -> Hs (h1), rows = tokens, stride HPAD
#pragma unroll
  for (int jt = 0; jt < 4; ++jt) {
    const int jbase = wave * 64 + jt * 16 + q * 4;
    const float4 bb = *(const float4*)&b1[jbase];
#pragma unroll
    for (int tt = 0; tt < 4; ++tt) {
      const int t = tt * 16 + l15;
      float v0 = fmaxf(acc[jt][tt][0] + bb.x, 0.f);
      float v1 = fmaxf(acc[jt][tt][1] + bb.y, 0.f);
      float v2 = fmaxf(acc[jt][tt][2] + bb.z, 0.f);
      float v3 = fmaxf(acc[jt][tt][3] + bb.w, 0.f);
      *(uint2*)&Hs[t * HPAD + jbase] = make_uint2(pkbf(v0, v1), pkbf(v2, v3));
    }
  }
  __syncthreads();                       // barrier 1: h1 visible

  // ---------------- layer 2: K = 256, A = W2^T, B = h1 ----------------
  for (int jt = 0; jt < 4; ++jt)
    for (int tt = 0; tt < 4; ++tt)
      acc[jt][tt] = (floatx4){0.f, 0.f, 0.f, 0.f};
#pragma unroll
  for (int kc = 0; kc < 8; ++kc) {
    bf16x8 a[4], b[4];
#pragma unroll
    for (int jt = 0; jt < 4; ++jt)
      a[jt] = *(const bf16x8*)(pW2 + ((((wave * 4 + jt) * 8 + kc) * 64 + lane) << 3));
#pragma unroll
    for (int tt = 0; tt < 4; ++tt)
      b[tt] = *(const bf16x8*)&Hs[(tt * 16 + l15) * HPAD + kc * 32 + q * 8];
#pragma unroll
    for (int jt = 0; jt < 4; ++jt)
#pragma unroll
      for (int tt = 0; tt < 4; ++tt)
        acc[jt][tt] = __builtin_amdgcn_mfma_f32_16x16x32_bf16(
            a[jt], b[tt], acc[jt][tt], 0, 0, 0);
  }
  __syncthreads();                       // barrier 2: h1 reads done
#pragma unroll
  for (int jt = 0; jt < 4; ++jt) {
    const int jbase = wave * 64 + jt * 16 + q * 4;
    const float4 bb = *(const float4*)&b2[jbase];
#pragma unroll
    for (int tt = 0; tt < 4; ++tt) {
      const int t = tt * 16 + l15;
      float v0 = fmaxf(acc[jt][tt][0] + bb.x, 0.f);
      float v1 = fmaxf(acc[jt][tt][1] + bb.y, 0.f);
      float v2 = fmaxf(acc[jt][tt][2] + bb.z, 0.f);
      float v3 = fmaxf(acc[jt][tt][3] + bb.w, 0.f);
      *(uint2*)&Hs[t * HPAD + jbase] = make_uint2(pkbf(v0, v1), pkbf(v2, v3));
    }
  }
  __syncthreads();                       // barrier 3: h2 visible

  // ---------------- layer 3: K = 256, A = W3^T, B = h2, fused mean ---------
  for (int jt = 0; jt < 4; ++jt)
    for (int tt = 0; tt < 4; ++tt)
      acc[jt][tt] = (floatx4){0.f, 0.f, 0.f, 0.f};
#pragma unroll
  for (int kc = 0; kc < 8; ++kc) {
    bf16x8 a[4], b[4];
#pragma unroll
    for (int jt = 0; jt < 4; ++jt)
      a[jt] = *(const bf16x8*)(pW3 + ((((wave * 4 + jt) * 8 + kc) * 64 + lane) << 3));
#pragma unroll
    for (int tt = 0; tt < 4; ++tt)
      b[tt] = *(const bf16x8*)&Hs[(tt * 16 + l15) * HPAD + kc * 32 + q * 8];
#pragma unroll
    for (int jt = 0; jt < 4; ++jt)
#pragma unroll
      for (int tt = 0; tt < 4; ++tt)
        acc[jt][tt] = __builtin_amdgcn_mfma_f32_16x16x32_bf16(
            a[jt], b[tt], acc[jt][tt], 0, 0, 0);
  }

  // bias + relu + token-sum: local over 4 t-tiles, then butterfly over the
  // 16-lane l15 subgroup (masks 1,2,4,8 stay inside it); l15==0 lanes commit.
  const int batch = blockIdx.x >> 6;     // / TPB
#pragma unroll
  for (int jt = 0; jt < 4; ++jt) {
    const int jbase = wave * 64 + jt * 16 + q * 4;
    const float4 bb = *(const float4*)&b3[jbase];
    float s0 = 0.f, s1 = 0.f, s2 = 0.f, s3 = 0.f;
#pragma unroll
    for (int tt = 0; tt < 4; ++tt) {
      s0 += fmaxf(acc[jt][tt][0] + bb.x, 0.f);
      s1 += fmaxf(acc[jt][tt][1] + bb.y, 0.f);
      s2 += fmaxf(acc[jt][tt][2] + bb.z, 0.f);
      s3 += fmaxf(acc[jt][tt][3] + bb.w, 0.f);
    }
#pragma unroll
    for (int m = 1; m <= 8; m <<= 1) {
      s0 += __shfl_xor(s0, m, 64);
      s1 += __shfl_xor(s1, m, 64);
      s2 += __shfl_xor(s2, m, 64);
      s3 += __shfl_xor(s3, m, 64);
    }
    if (l15 == 0) {
      float* mp = &msum[batch * NHID + jbase];
      atomicAdd(mp + 0, s0);
      atomicAdd(mp + 1, s1);
      atomicAdd(mp + 2, s2);
      atomicAdd(mp + 3, s3);
    }
  }
}

// ---------------------------------------------------------------------------
// Decoder, split for parallelism (R2: monolithic = 32 blocks, 75us).
// ---------------------------------------------------------------------------
__global__ __launch_bounds__(256) void dec1_kernel(
    const float* __restrict__ msum, const float* __restrict__ D1,
    const float* __restrict__ c1, float* __restrict__ d1out) {
  __shared__ float p[NHID];
  __shared__ float red[256];
  const int b = blockIdx.y, jc = blockIdx.x, t = threadIdx.x;
  {
    float m = msum[b * NHID + t] * (1.f / NTOK);
    p[t] = m * m;                       // relu(m^2) == m^2
  }
  __syncthreads();
  const int j  = jc * 64 + (t & 63);
  const int kc = t >> 6;                // 0..3, 64 k's each
  float s = 0.f;
  for (int k = kc * 64; k < kc * 64 + 64; ++k)
    s += p[k] * D1[k * NDEC + j];
  red[t] = s;
  __syncthreads();
  if (t < 64) {
    float v = red[t] + red[64 + t] + red[128 + t] + red[192 + t]
            + c1[jc * 64 + t];
    d1out[b * NDEC + jc * 64 + t] = fmaxf(v, 0.f);
  }
}

__global__ __launch_bounds__(256) void dec2_kernel(
    const float* __restrict__ d1, const float* __restrict__ D2,
    const float* __restrict__ c2, float* __restrict__ d2out) {
  __shared__ float h[NDEC];
  __shared__ float red[256];
  const int b = blockIdx.y, jc = blockIdx.x, t = threadIdx.x;
  h[t]       = d1[b * NDEC + t];
  h[t + 256] = d1[b * NDEC + t + 256];
  __syncthreads();
  const int j  = jc * 64 + (t & 63);
  const int kc = t >> 6;                // 0..3, 128 k's each
  float s = 0.f;
  for (int k = kc * 128; k < kc * 128 + 128; ++k)
    s += h[k] * D2[k * NDEC + j];
  red[t] = s;
  __syncthreads();
  if (t < 64) {
    float v = red[t] + red[64 + t] + red[128 + t] + red[192 + t]
            + c2[jc * 64 + t];
    d2out[b * NDEC + jc * 64 + t] = fmaxf(v, 0.f);
  }
}

__global__ __launch_bounds__(256) void dec3_kernel(
    const float* __restrict__ d2, const float* __restrict__ D3,
    const float* __restrict__ c3, float* __restrict__ out) {
  __shared__ float h[NDEC];
  __shared__ float red[256];
  const int b = blockIdx.x, t = threadIdx.x;
  h[t]       = d2[b * NDEC + t];
  h[t + 256] = d2[b * NDEC + t + 256];
  __syncthreads();
  const int j  = t & 15;                // 16 slots, NOUTC=10 valid
  const int kc = t >> 4;                // 16 chunks x 32 k's
  float s = 0.f;
  if (j < NOUTC)
    for (int k = kc * 32; k < kc * 32 + 32; ++k)
      s += h[k] * D3[k * NOUTC + j];
  red[t] = s;
  __syncthreads();
  if (t < NOUTC) {
    float v = c3[t];
    for (int i = 0; i < 16; ++i) v += red[i * 16 + t];
    out[b * NOUTC + t] = v;
  }
}

// ---------------------------------------------------------------------------
extern "C" void kernel_launch(void* const* d_in, const int* in_sizes, int n_in,
                              void* d_out, int out_size, void* d_ws, size_t ws_size,
                              hipStream_t stream) {
  const float* x  = (const float*)d_in[0];
  const float* W1 = (const float*)d_in[1];
  const float* b1 = (const float*)d_in[2];
  const float* W2 = (const float*)d_in[3];
  const float* b2 = (const float*)d_in[4];
  const float* W3 = (const float*)d_in[5];
  const float* b3 = (const float*)d_in[6];
  const float* D1 = (const float*)d_in[7];
  const float* c1 = (const float*)d_in[8];
  const float* D2 = (const float*)d_in[9];
  const float* c2 = (const float*)d_in[10];
  const float* D3 = (const float*)d_in[11];
  const float* c3 = (const float*)d_in[12];

  // ws layout: [0,320K) packed bf16 W | [384K,416K) msum | [448K,512K) d1 |
  //            [512K,576K) d2
  uint16_t* pW   = (uint16_t*)d_ws;
  float*    msum = (float*)((char*)d_ws + 384 * 1024);
  float*    d1s  = (float*)((char*)d_ws + 448 * 1024);
  float*    d2s  = (float*)((char*)d_ws + 512 * 1024);

  pack_weights<<<640, 256, 0, stream>>>(W1, W2, W3, pW, msum);
  encoder<<<NBLK, 256, 0, stream>>>(x, pW, b1, b2, b3, msum);
  dec1_kernel<<<dim3(8, BATCH), 256, 0, stream>>>(msum, D1, c1, d1s);
  dec2_kernel<<<dim3(8, BATCH), 256, 0, stream>>>(d1s, D2, c2, d2s);
  dec3_kernel<<<BATCH, 256, 0, stream>>>(d2s, D3, c3, (float*)d_out);
}

// Round 7
// 194.681 us; speedup vs baseline: 1.1739x; 1.1698x over previous
//
#include <hip/hip_runtime.h>
#include <hip/hip_bf16.h>
#include <stdint.h>

// ---------------------------------------------------------------------------
// TensorNet: fused encoder MLP (128->256->256->256, relu) over 32x4096 tokens,
// per-batch mean -> p = relu(m^2) -> decoder MLP (256->512->512->10).
// Inputs/outputs fp32. Encoder via bf16 MFMA (A=weights M=hidden, B=act
// N=tokens) + fp32 accum.
// History: R4 (LDS x-staging + LDS-scratch reduction) = 66us encoder, best.
// R5/R6 (direct-global layer1 + shfl butterfly) = 93-96us — REGRESSION:
// 4x-redundant scattered x reads + 64 bpermutes beat the 2 barriers saved.
// R7 = R4 structure + ONE fix: pad the scratch reduction row stride 16->17
// float4 so the final read's bank = (4c+4l+r)%32 (2-way, free) instead of
// (4l+r)%32 (16-way, ~3M conflict cycles).
// ---------------------------------------------------------------------------

#define NIN   128
#define NHID  256
#define NDEC  512
#define NOUTC 10
#define BATCH 32
#define NTOK  4096
#define MTILE 64
#define TPB   64               // encoder blocks per batch (4096/64)
#define NBLK  (BATCH * TPB)    // 2048 encoder blocks
#define XPAD  136              // x-tile LDS row stride (bf16 elems)
#define HPAD  264              // h-tile LDS row stride (bf16 elems), 528B rows

typedef short bf16x8 __attribute__((ext_vector_type(8)));
typedef float floatx4 __attribute__((ext_vector_type(4)));

__device__ __forceinline__ uint16_t f2b(float f) {
  union { float f; uint32_t u; } v; v.f = f;
  uint32_t r = v.u + 0x7FFFu + ((v.u >> 16) & 1u);   // RNE
  return (uint16_t)(r >> 16);
}
__device__ __forceinline__ uint32_t pkbf(float lo, float hi) {
  __hip_bfloat162 h = __float22bfloat162_rn(float2{lo, hi});  // v_cvt_pk_bf16_f32
  union { __hip_bfloat162 h; uint32_t u; } c; c.h = h;
  return c.u;
}

// ---------------------------------------------------------------------------
// Pack W1/W2/W3 (fp32 [K][256] row-major) into bf16 MFMA-fragment order:
//   packed[((mt*KC + kc)*64 + lane)*8 + j] =
//       bf16( W[kc*32 + (lane>>4)*8 + j][mt*16 + (lane&15)] )
// Serves as the encoder's A-operand (A[m][k] = W[k][m], m=hidden out).
// Also zero-inits the msum accumulator (poisoned 0xAA by the harness).
// ---------------------------------------------------------------------------
__global__ __launch_bounds__(256) void pack_weights(
    const float* __restrict__ W1, const float* __restrict__ W2,
    const float* __restrict__ W3, uint16_t* __restrict__ out,
    float* __restrict__ msum) {
  int p = blockIdx.x * blockDim.x + threadIdx.x;
  if (p < BATCH * NHID) msum[p] = 0.f;
  const float* W; int K; int base;
  if (p < 32768)      { W = W1; K = NIN;  base = 0; }
  else if (p < 98304) { W = W2; K = NHID; base = 32768; p -= 32768; }
  else                { W = W3; K = NHID; base = 98304; p -= 98304; }
  int j    = p & 7;
  int lane = (p >> 3) & 63;
  int rest = p >> 9;
  int KC = K >> 5;               // K/32 k-chunks
  int kc = rest % KC;
  int mt = rest / KC;
  int m = mt * 16 + (lane & 15);
  int k = kc * 32 + ((lane >> 4) << 3) + j;
  out[base + (((mt * KC + kc) * 64 + lane) << 3) + j] = f2b(W[k * NHID + m]);
}

// ---------------------------------------------------------------------------
// Fused encoder. Block = 256 thr (4 waves), 64 tokens. Wave w owns hidden
// rows [64w, 64w+64) (A = packed weights); token tiles shared (B from LDS).
// D tile: lane holds j = 64w+jt*16+q*4+r (contiguous run) at t = tt*16+l15.
// NOTE: plain __launch_bounds__(256) — (256,4) forces VGPR=64 < the 64-reg
// accumulator array and spills to scratch (R5: +20MB HBM writes).
// ---------------------------------------------------------------------------
__global__ __launch_bounds__(256) void encoder(
    const float* __restrict__ x,        // [BATCH*NTOK][NIN] fp32
    const uint16_t* __restrict__ pW,    // packed bf16 weights
    const float* __restrict__ b1,
    const float* __restrict__ b2,
    const float* __restrict__ b3,
    float* __restrict__ msum) {         // [BATCH][NHID] fp32 accum
  __shared__ uint16_t Hs[MTILE * HPAD]; // 33792 B; x-tile & scratch alias

  const int tid  = threadIdx.x;
  const int wave = tid >> 6;
  const int lane = tid & 63;
  const int l15  = lane & 15;
  const int q    = lane >> 4;
  const int tok0 = blockIdx.x * MTILE;

  const uint16_t* pW1 = pW;             // KC=4
  const uint16_t* pW2 = pW + 32768;     // KC=8
  const uint16_t* pW3 = pW + 98304;     // KC=8

  // ---- stage x tile: fp32 -> bf16 (packed cvt), rows stride XPAD ----
  {
    const int row = tid >> 2;
    const int c0  = (tid & 3) * 32;
    const float* xr = x + (size_t)(tok0 + row) * NIN + c0;
    for (int i = 0; i < 8; ++i) {
      float4 v = *(const float4*)(xr + i * 4);
      uint2 u = make_uint2(pkbf(v.x, v.y), pkbf(v.z, v.w));
      *(uint2*)&Hs[row * XPAD + c0 + i * 4] = u;
    }
  }
  __syncthreads();

  floatx4 acc[4][4];   // [jt][tt]

  // ---------------- layer 1: K = 128, A = W1^T, B = x ----------------
  for (int jt = 0; jt < 4; ++jt)
    for (int tt = 0; tt < 4; ++tt)
      acc[jt][tt] = (floatx4){0.f, 0.f, 0.f, 0.f};
#pragma unroll
  for (int kc = 0; kc < 4; ++kc) {
    bf16x8 a[4], b[4];
#pragma unroll
    for (int jt = 0; jt < 4; ++jt)
      a[jt] = *(const bf16x8*)(pW1 + ((((wave * 4 + jt) * 4 + kc) * 64 + lane) << 3));
#pragma unroll
    for (int tt = 0; tt < 4; ++tt)
      b[tt] = *(const bf16x8*)&Hs[(tt * 16 + l15) * XPAD + kc * 32 + q * 8];
#pragma unroll
    for (int jt = 0; jt < 4; ++jt)
#pragma unroll
      for (int tt = 0; tt < 4; ++tt)
        acc[jt][tt] = __builtin_amdgcn_mfma_f32_16x16x32_bf16(
            a[jt], b[tt], acc[jt][tt], 0, 0, 0);
  }
  __syncthreads();   // all x-tile reads done before h1 overwrites the region

  // bias + relu -> Hs (h1), rows = tokens, stride HPAD
#pragma unroll
  for (int jt = 0; jt < 4; ++jt) {
    const int jbase = wave * 64 + jt * 16 + q * 4;
    const float4 bb = *(const float4*)&b1[jbase];
#pragma unroll
    for (int tt = 0; tt < 4; ++tt) {
      const int t = tt * 16 + l15;
      float v0 = fmaxf(acc[jt][tt][0] + bb.x, 0.f);
      float v1 = fmaxf(acc[jt][tt][1] + bb.y, 0.f);
      float v2 = fmaxf(acc[jt][tt][2] + bb.z, 0.f);
      float v3 = fmaxf(acc[jt][tt][3] + bb.w, 0.f);
      *(uint2*)&Hs[t * HPAD + jbase] = make_uint2(pkbf(v0, v1), pkbf(v2, v3));
    }
  }
  __syncthreads();

  // ---------------- layer 2: K = 256, A = W2^T, B = h1 ----------------
  for (int jt = 0; jt < 4; ++jt)
    for (int tt = 0; tt < 4; ++tt)
      acc[jt][tt] = (floatx4){0.f, 0.f, 0.f, 0.f};
#pragma unroll
  for (int kc = 0; kc < 8; ++kc) {
    bf16x8 a[4], b[4];
#pragma unroll
    for (int jt = 0; jt < 4; ++jt)
      a[jt] = *(const bf16x8*)(pW2 + ((((wave * 4 + jt) * 8 + kc) * 64 + lane) << 3));
#pragma unroll
    for (int tt = 0; tt < 4; ++tt)
      b[tt] = *(const bf16x8*)&Hs[(tt * 16 + l15) * HPAD + kc * 32 + q * 8];
#pragma unroll
    for (int jt = 0; jt < 4; ++jt)
#pragma unroll
      for (int tt = 0; tt < 4; ++tt)
        acc[jt][tt] = __builtin_amdgcn_mfma_f32_16x16x32_bf16(
            a[jt], b[tt], acc[jt][tt], 0, 0, 0);
  }
  __syncthreads();   // everyone done READING h1 before overwrite
#pragma unroll
  for (int jt = 0; jt < 4; ++jt) {
    const int jbase = wave * 64 + jt * 16 + q * 4;
    const float4 bb = *(const float4*)&b2[jbase];
#pragma unroll
    for (int tt = 0; tt < 4; ++tt) {
      const int t = tt * 16 + l15;
      float v0 = fmaxf(acc[jt][tt][0] + bb.x, 0.f);
      float v1 = fmaxf(acc[jt][tt][1] + bb.y, 0.f);
      float v2 = fmaxf(acc[jt][tt][2] + bb.z, 0.f);
      float v3 = fmaxf(acc[jt][tt][3] + bb.w, 0.f);
      *(uint2*)&Hs[t * HPAD + jbase] = make_uint2(pkbf(v0, v1), pkbf(v2, v3));
    }
  }
  __syncthreads();

  // ---------------- layer 3: K = 256, A = W3^T, B = h2, fused mean ---------
  for (int jt = 0; jt < 4; ++jt)
    for (int tt = 0; tt < 4; ++tt)
      acc[jt][tt] = (floatx4){0.f, 0.f, 0.f, 0.f};
#pragma unroll
  for (int kc = 0; kc < 8; ++kc) {
    bf16x8 a[4], b[4];
#pragma unroll
    for (int jt = 0; jt < 4; ++jt)
      a[jt] = *(const bf16x8*)(pW3 + ((((wave * 4 + jt) * 8 + kc) * 64 + lane) << 3));
#pragma unroll
    for (int tt = 0; tt < 4; ++tt)
      b[tt] = *(const bf16x8*)&Hs[(tt * 16 + l15) * HPAD + kc * 32 + q * 8];
#pragma unroll
    for (int jt = 0; jt < 4; ++jt)
#pragma unroll
      for (int tt = 0; tt < 4; ++tt)
        acc[jt][tt] = __builtin_amdgcn_mfma_f32_16x16x32_bf16(
            a[jt], b[tt], acc[jt][tt], 0, 0, 0);
  }
  __syncthreads();   // all h2 reads done before scratch overwrites Hs

  // bias + relu + partial token-sum (over this lane's 4 t-tiles at l15).
  // Scratch rows padded 16->17 float4: final-read bank = (4c+4l+r)%32
  // (2-way max) instead of (4l+r)%32 (16-way) — R4's 3M conflict cycles.
  {
    float4* scratch = (float4*)Hs;      // 64 rows x 17 float4 = 17408 B
#pragma unroll
    for (int jt = 0; jt < 4; ++jt) {
      const int jbase = wave * 64 + jt * 16 + q * 4;
      const float4 bb = *(const float4*)&b3[jbase];
      float s0 = 0.f, s1 = 0.f, s2 = 0.f, s3 = 0.f;
#pragma unroll
      for (int tt = 0; tt < 4; ++tt) {
        s0 += fmaxf(acc[jt][tt][0] + bb.x, 0.f);
        s1 += fmaxf(acc[jt][tt][1] + bb.y, 0.f);
        s2 += fmaxf(acc[jt][tt][2] + bb.z, 0.f);
        s3 += fmaxf(acc[jt][tt][3] + bb.w, 0.f);
      }
      scratch[((wave * 4 + jt) * 4 + q) * 17 + l15] =
          (float4){s0, s1, s2, s3};
    }
  }
  __syncthreads();
  {
    const int c = tid >> 2;             // (wave*4+jt)*4+q
    const int r = tid & 3;
    const float* sf = (const float*)Hs;
    float v = 0.f;
#pragma unroll
    for (int l = 0; l < 16; ++l)
      v += sf[c * 68 + l * 4 + r];      // padded stride: 17 float4 = 68 f
    const int wv = c >> 4, jt = (c >> 2) & 3, qq = c & 3;
    const int j = wv * 64 + jt * 16 + qq * 4 + r;
    const int batch = blockIdx.x >> 6;  // / TPB
    atomicAdd(&msum[batch * NHID + j], v);
  }
}

// ---------------------------------------------------------------------------
// Decoder, split for parallelism (R2: monolithic = 32 blocks, 75us).
// ---------------------------------------------------------------------------
__global__ __launch_bounds__(256) void dec1_kernel(
    const float* __restrict__ msum, const float* __restrict__ D1,
    const float* __restrict__ c1, float* __restrict__ d1out) {
  __shared__ float p[NHID];
  __shared__ float red[256];
  const int b = blockIdx.y, jc = blockIdx.x, t = threadIdx.x;
  {
    float m = msum[b * NHID + t] * (1.f / NTOK);
    p[t] = m * m;                       // relu(m^2) == m^2
  }
  __syncthreads();
  const int j  = jc * 64 + (t & 63);
  const int kc = t >> 6;                // 0..3, 64 k's each
  float s = 0.f;
  for (int k = kc * 64; k < kc * 64 + 64; ++k)
    s += p[k] * D1[k * NDEC + j];
  red[t] = s;
  __syncthreads();
  if (t < 64) {
    float v = red[t] + red[64 + t] + red[128 + t] + red[192 + t]
            + c1[jc * 64 + t];
    d1out[b * NDEC + jc * 64 + t] = fmaxf(v, 0.f);
  }
}

__global__ __launch_bounds__(256) void dec2_kernel(
    const float* __restrict__ d1, const float* __restrict__ D2,
    const float* __restrict__ c2, float* __restrict__ d2out) {
  __shared__ float h[NDEC];
  __shared__ float red[256];
  const int b = blockIdx.y, jc = blockIdx.x, t = threadIdx.x;
  h[t]       = d1[b * NDEC + t];
  h[t + 256] = d1[b * NDEC + t + 256];
  __syncthreads();
  const int j  = jc * 64 + (t & 63);
  const int kc = t >> 6;                // 0..3, 128 k's each
  float s = 0.f;
  for (int k = kc * 128; k < kc * 128 + 128; ++k)
    s += h[k] * D2[k * NDEC + j];
  red[t] = s;
  __syncthreads();
  if (t < 64) {
    float v = red[t] + red[64 + t] + red[128 + t] + red[192 + t]
            + c2[jc * 64 + t];
    d2out[b * NDEC + jc * 64 + t] = fmaxf(v, 0.f);
  }
}

__global__ __launch_bounds__(256) void dec3_kernel(
    const float* __restrict__ d2, const float* __restrict__ D3,
    const float* __restrict__ c3, float* __restrict__ out) {
  __shared__ float h[NDEC];
  __shared__ float red[256];
  const int b = blockIdx.x, t = threadIdx.x;
  h[t]       = d2[b * NDEC + t];
  h[t + 256] = d2[b * NDEC + t + 256];
  __syncthreads();
  const int j  = t & 15;                // 16 slots, NOUTC=10 valid
  const int kc = t >> 4;                // 16 chunks x 32 k's
  float s = 0.f;
  if (j < NOUTC)
    for (int k = kc * 32; k < kc * 32 + 32; ++k)
      s += h[k] * D3[k * NOUTC + j];
  red[t] = s;
  __syncthreads();
  if (t < NOUTC) {
    float v = c3[t];
    for (int i = 0; i < 16; ++i) v += red[i * 16 + t];
    out[b * NOUTC + t] = v;
  }
}

// ---------------------------------------------------------------------------
extern "C" void kernel_launch(void* const* d_in, const int* in_sizes, int n_in,
                              void* d_out, int out_size, void* d_ws, size_t ws_size,
                              hipStream_t stream) {
  const float* x  = (const float*)d_in[0];
  const float* W1 = (const float*)d_in[1];
  const float* b1 = (const float*)d_in[2];
  const float* W2 = (const float*)d_in[3];
  const float* b2 = (const float*)d_in[4];
  const float* W3 = (const float*)d_in[5];
  const float* b3 = (const float*)d_in[6];
  const float* D1 = (const float*)d_in[7];
  const float* c1 = (const float*)d_in[8];
  const float* D2 = (const float*)d_in[9];
  const float* c2 = (const float*)d_in[10];
  const float* D3 = (const float*)d_in[11];
  const float* c3 = (const float*)d_in[12];

  // ws layout: [0,320K) packed bf16 W | [384K,416K) msum | [448K,512K) d1 |
  //            [512K,576K) d2
  uint16_t* pW   = (uint16_t*)d_ws;
  float*    msum = (float*)((char*)d_ws + 384 * 1024);
  float*    d1s  = (float*)((char*)d_ws + 448 * 1024);
  float*    d2s  = (float*)((char*)d_ws + 512 * 1024);

  pack_weights<<<640, 256, 0, stream>>>(W1, W2, W3, pW, msum);
  encoder<<<NBLK, 256, 0, stream>>>(x, pW, b1, b2, b3, msum);
  dec1_kernel<<<dim3(8, BATCH), 256, 0, stream>>>(msum, D1, c1, d1s);
  dec2_kernel<<<dim3(8, BATCH), 256, 0, stream>>>(d1s, D2, c2, d2s);
  dec3_kernel<<<BATCH, 256, 0, stream>>>(d2s, D3, c3, (float*)d_out);
}

// Round 8
// 176.370 us; speedup vs baseline: 1.2957x; 1.1038x over previous
//
#include <hip/hip_runtime.h>
#include <hip/hip_bf16.h>
#include <stdint.h>

// ---------------------------------------------------------------------------
// TensorNet: fused encoder MLP (128->256->256->256, relu) over 32x4096 tokens,
// per-batch mean -> p = relu(m^2) -> decoder MLP (256->512->512->10).
// Inputs/outputs fp32. Encoder via bf16 MFMA (A=weights M=hidden, B=act
// N=tokens) + fp32 accum.
// R7 found: ~20us PER KERNEL LAUNCH overhead (dur_us - dispatch work is
// ~19-21us x kernel count across R2-R7). 5 kernels = ~100us of the 194.7.
// R8: merge dec1/dec2/dec3 into ONE 32x1024 kernel (16 waves/block; K split
// 2 threads/output + LDS tree-reduce -> longest per-thread loop 256, unlike
// R2's 4-wave serial-512 monolith). 5 kernels -> 3.
// ---------------------------------------------------------------------------

#define NIN   128
#define NHID  256
#define NDEC  512
#define NOUTC 10
#define BATCH 32
#define NTOK  4096
#define MTILE 64
#define TPB   64               // encoder blocks per batch (4096/64)
#define NBLK  (BATCH * TPB)    // 2048 encoder blocks
#define XPAD  136              // x-tile LDS row stride (bf16 elems)
#define HPAD  264              // h-tile LDS row stride (bf16 elems), 528B rows

typedef short bf16x8 __attribute__((ext_vector_type(8)));
typedef float floatx4 __attribute__((ext_vector_type(4)));

__device__ __forceinline__ uint16_t f2b(float f) {
  union { float f; uint32_t u; } v; v.f = f;
  uint32_t r = v.u + 0x7FFFu + ((v.u >> 16) & 1u);   // RNE
  return (uint16_t)(r >> 16);
}
__device__ __forceinline__ uint32_t pkbf(float lo, float hi) {
  __hip_bfloat162 h = __float22bfloat162_rn(float2{lo, hi});  // v_cvt_pk_bf16_f32
  union { __hip_bfloat162 h; uint32_t u; } c; c.h = h;
  return c.u;
}

// ---------------------------------------------------------------------------
// Pack W1/W2/W3 (fp32 [K][256] row-major) into bf16 MFMA-fragment order:
//   packed[((mt*KC + kc)*64 + lane)*8 + j] =
//       bf16( W[kc*32 + (lane>>4)*8 + j][mt*16 + (lane&15)] )
// Serves as the encoder's A-operand (A[m][k] = W[k][m], m=hidden out).
// Also zero-inits the msum accumulator (poisoned 0xAA by the harness).
// ---------------------------------------------------------------------------
__global__ __launch_bounds__(256) void pack_weights(
    const float* __restrict__ W1, const float* __restrict__ W2,
    const float* __restrict__ W3, uint16_t* __restrict__ out,
    float* __restrict__ msum) {
  int p = blockIdx.x * blockDim.x + threadIdx.x;
  if (p < BATCH * NHID) msum[p] = 0.f;
  const float* W; int K; int base;
  if (p < 32768)      { W = W1; K = NIN;  base = 0; }
  else if (p < 98304) { W = W2; K = NHID; base = 32768; p -= 32768; }
  else                { W = W3; K = NHID; base = 98304; p -= 98304; }
  int j    = p & 7;
  int lane = (p >> 3) & 63;
  int rest = p >> 9;
  int KC = K >> 5;               // K/32 k-chunks
  int kc = rest % KC;
  int mt = rest / KC;
  int m = mt * 16 + (lane & 15);
  int k = kc * 32 + ((lane >> 4) << 3) + j;
  out[base + (((mt * KC + kc) * 64 + lane) << 3) + j] = f2b(W[k * NHID + m]);
}

// ---------------------------------------------------------------------------
// Fused encoder. Block = 256 thr (4 waves), 64 tokens. Wave w owns hidden
// rows [64w, 64w+64) (A = packed weights); token tiles shared (B from LDS).
// D tile: lane holds j = 64w+jt*16+q*4+r (contiguous run) at t = tt*16+l15.
// NOTE: plain __launch_bounds__(256) — (256,4) forces VGPR=64 < the 64-reg
// accumulator array and spills to scratch (R5: +20MB HBM writes).
// ---------------------------------------------------------------------------
__global__ __launch_bounds__(256) void encoder(
    const float* __restrict__ x,        // [BATCH*NTOK][NIN] fp32
    const uint16_t* __restrict__ pW,    // packed bf16 weights
    const float* __restrict__ b1,
    const float* __restrict__ b2,
    const float* __restrict__ b3,
    float* __restrict__ msum) {         // [BATCH][NHID] fp32 accum
  __shared__ uint16_t Hs[MTILE * HPAD]; // 33792 B; x-tile & scratch alias

  const int tid  = threadIdx.x;
  const int wave = tid >> 6;
  const int lane = tid & 63;
  const int l15  = lane & 15;
  const int q    = lane >> 4;
  const int tok0 = blockIdx.x * MTILE;

  const uint16_t* pW1 = pW;             // KC=4
  const uint16_t* pW2 = pW + 32768;     // KC=8
  const uint16_t* pW3 = pW + 98304;     // KC=8

  // ---- stage x tile: fp32 -> bf16 (packed cvt), rows stride XPAD ----
  {
    const int row = tid >> 2;
    const int c0  = (tid & 3) * 32;
    const float* xr = x + (size_t)(tok0 + row) * NIN + c0;
    for (int i = 0; i < 8; ++i) {
      float4 v = *(const float4*)(xr + i * 4);
      uint2 u = make_uint2(pkbf(v.x, v.y), pkbf(v.z, v.w));
      *(uint2*)&Hs[row * XPAD + c0 + i * 4] = u;
    }
  }
  __syncthreads();

  floatx4 acc[4][4];   // [jt][tt]

  // ---------------- layer 1: K = 128, A = W1^T, B = x ----------------
  for (int jt = 0; jt < 4; ++jt)
    for (int tt = 0; tt < 4; ++tt)
      acc[jt][tt] = (floatx4){0.f, 0.f, 0.f, 0.f};
#pragma unroll
  for (int kc = 0; kc < 4; ++kc) {
    bf16x8 a[4], b[4];
#pragma unroll
    for (int jt = 0; jt < 4; ++jt)
      a[jt] = *(const bf16x8*)(pW1 + ((((wave * 4 + jt) * 4 + kc) * 64 + lane) << 3));
#pragma unroll
    for (int tt = 0; tt < 4; ++tt)
      b[tt] = *(const bf16x8*)&Hs[(tt * 16 + l15) * XPAD + kc * 32 + q * 8];
#pragma unroll
    for (int jt = 0; jt < 4; ++jt)
#pragma unroll
      for (int tt = 0; tt < 4; ++tt)
        acc[jt][tt] = __builtin_amdgcn_mfma_f32_16x16x32_bf16(
            a[jt], b[tt], acc[jt][tt], 0, 0, 0);
  }
  __syncthreads();   // all x-tile reads done before h1 overwrites the region

  // bias + relu -> Hs (h1), rows = tokens, stride HPAD
#pragma unroll
  for (int jt = 0; jt < 4; ++jt) {
    const int jbase = wave * 64 + jt * 16 + q * 4;
    const float4 bb = *(const float4*)&b1[jbase];
#pragma unroll
    for (int tt = 0; tt < 4; ++tt) {
      const int t = tt * 16 + l15;
      float v0 = fmaxf(acc[jt][tt][0] + bb.x, 0.f);
      float v1 = fmaxf(acc[jt][tt][1] + bb.y, 0.f);
      float v2 = fmaxf(acc[jt][tt][2] + bb.z, 0.f);
      float v3 = fmaxf(acc[jt][tt][3] + bb.w, 0.f);
      *(uint2*)&Hs[t * HPAD + jbase] = make_uint2(pkbf(v0, v1), pkbf(v2, v3));
    }
  }
  __syncthreads();

  // ---------------- layer 2: K = 256, A = W2^T, B = h1 ----------------
  for (int jt = 0; jt < 4; ++jt)
    for (int tt = 0; tt < 4; ++tt)
      acc[jt][tt] = (floatx4){0.f, 0.f, 0.f, 0.f};
#pragma unroll
  for (int kc = 0; kc < 8; ++kc) {
    bf16x8 a[4], b[4];
#pragma unroll
    for (int jt = 0; jt < 4; ++jt)
      a[jt] = *(const bf16x8*)(pW2 + ((((wave * 4 + jt) * 8 + kc) * 64 + lane) << 3));
#pragma unroll
    for (int tt = 0; tt < 4; ++tt)
      b[tt] = *(const bf16x8*)&Hs[(tt * 16 + l15) * HPAD + kc * 32 + q * 8];
#pragma unroll
    for (int jt = 0; jt < 4; ++jt)
#pragma unroll
      for (int tt = 0; tt < 4; ++tt)
        acc[jt][tt] = __builtin_amdgcn_mfma_f32_16x16x32_bf16(
            a[jt], b[tt], acc[jt][tt], 0, 0, 0);
  }
  __syncthreads();   // everyone done READING h1 before overwrite
#pragma unroll
  for (int jt = 0; jt < 4; ++jt) {
    const int jbase = wave * 64 + jt * 16 + q * 4;
    const float4 bb = *(const float4*)&b2[jbase];
#pragma unroll
    for (int tt = 0; tt < 4; ++tt) {
      const int t = tt * 16 + l15;
      float v0 = fmaxf(acc[jt][tt][0] + bb.x, 0.f);
      float v1 = fmaxf(acc[jt][tt][1] + bb.y, 0.f);
      float v2 = fmaxf(acc[jt][tt][2] + bb.z, 0.f);
      float v3 = fmaxf(acc[jt][tt][3] + bb.w, 0.f);
      *(uint2*)&Hs[t * HPAD + jbase] = make_uint2(pkbf(v0, v1), pkbf(v2, v3));
    }
  }
  __syncthreads();

  // ---------------- layer 3: K = 256, A = W3^T, B = h2, fused mean ---------
  for (int jt = 0; jt < 4; ++jt)
    for (int tt = 0; tt < 4; ++tt)
      acc[jt][tt] = (floatx4){0.f, 0.f, 0.f, 0.f};
#pragma unroll
  for (int kc = 0; kc < 8; ++kc) {
    bf16x8 a[4], b[4];
#pragma unroll
    for (int jt = 0; jt < 4; ++jt)
      a[jt] = *(const bf16x8*)(pW3 + ((((wave * 4 + jt) * 8 + kc) * 64 + lane) << 3));
#pragma unroll
    for (int tt = 0; tt < 4; ++tt)
      b[tt] = *(const bf16x8*)&Hs[(tt * 16 + l15) * HPAD + kc * 32 + q * 8];
#pragma unroll
    for (int jt = 0; jt < 4; ++jt)
#pragma unroll
      for (int tt = 0; tt < 4; ++tt)
        acc[jt][tt] = __builtin_amdgcn_mfma_f32_16x16x32_bf16(
            a[jt], b[tt], acc[jt][tt], 0, 0, 0);
  }
  __syncthreads();   // all h2 reads done before scratch overwrites Hs

  // bias + relu + partial token-sum (over this lane's 4 t-tiles at l15).
  // Scratch rows padded 17 float4: final-read bank = (4c+4l+r)%32 (2-way).
  {
    float4* scratch = (float4*)Hs;      // 64 rows x 17 float4 = 17408 B
#pragma unroll
    for (int jt = 0; jt < 4; ++jt) {
      const int jbase = wave * 64 + jt * 16 + q * 4;
      const float4 bb = *(const float4*)&b3[jbase];
      float s0 = 0.f, s1 = 0.f, s2 = 0.f, s3 = 0.f;
#pragma unroll
      for (int tt = 0; tt < 4; ++tt) {
        s0 += fmaxf(acc[jt][tt][0] + bb.x, 0.f);
        s1 += fmaxf(acc[jt][tt][1] + bb.y, 0.f);
        s2 += fmaxf(acc[jt][tt][2] + bb.z, 0.f);
        s3 += fmaxf(acc[jt][tt][3] + bb.w, 0.f);
      }
      scratch[((wave * 4 + jt) * 4 + q) * 17 + l15] =
          (float4){s0, s1, s2, s3};
    }
  }
  __syncthreads();
  {
    const int c = tid >> 2;             // (wave*4+jt)*4+q
    const int r = tid & 3;
    const float* sf = (const float*)Hs;
    float v = 0.f;
#pragma unroll
    for (int l = 0; l < 16; ++l)
      v += sf[c * 68 + l * 4 + r];      // padded stride: 17 float4 = 68 f
    const int wv = c >> 4, jt = (c >> 2) & 3, qq = c & 3;
    const int j = wv * 64 + jt * 16 + qq * 4 + r;
    const int batch = blockIdx.x >> 6;  // / TPB
    atomicAdd(&msum[batch * NHID + j], v);
  }
}

// ---------------------------------------------------------------------------
// Merged decoder: one block per batch, 1024 threads (16 waves).
// Each layer splits K across 2 threads per output + LDS pair-reduce;
// longest per-thread loop = 256 (layer 2). R2's monolith failed with 4 waves
// and serial 256-512 loops; 16 waves hide the L2 latency.
// ---------------------------------------------------------------------------
__global__ __launch_bounds__(1024) void decoder(
    const float* __restrict__ msum,
    const float* __restrict__ D1, const float* __restrict__ c1,
    const float* __restrict__ D2, const float* __restrict__ c2,
    const float* __restrict__ D3, const float* __restrict__ c3,
    float* __restrict__ out) {
  __shared__ float p[NHID];
  __shared__ float d1[NDEC];
  __shared__ float d2[NDEC];
  __shared__ float red[1024];
  const int b = blockIdx.x, t = threadIdx.x;

  if (t < NHID) {
    float m = msum[b * NHID + t] * (1.f / NTOK);
    p[t] = m * m;                        // relu(m^2) == m^2
  }
  __syncthreads();

  const int j = t & 511;                 // output index
  const int h = t >> 9;                  // k-half 0/1

  // layer 1: K = 256 -> 128 per thread
  {
    float s = 0.f;
    for (int k = h * 128; k < h * 128 + 128; ++k)
      s += p[k] * D1[k * NDEC + j];
    red[t] = s;
    __syncthreads();
    if (t < NDEC)
      d1[t] = fmaxf(red[t] + red[512 + t] + c1[t], 0.f);
    __syncthreads();
  }

  // layer 2: K = 512 -> 256 per thread
  {
    float s = 0.f;
    for (int k = h * 256; k < h * 256 + 256; ++k)
      s += d1[k] * D2[k * NDEC + j];
    red[t] = s;
    __syncthreads();
    if (t < NDEC)
      d2[t] = fmaxf(red[t] + red[512 + t] + c2[t], 0.f);
    __syncthreads();
  }

  // layer 3: [512][10]; 64 k-chunks x 16 j-slots (10 valid)
  {
    const int j3 = t & 15;
    const int kc = t >> 4;               // 0..63, 8 k's each
    float s = 0.f;
    if (j3 < NOUTC)
      for (int k = kc * 8; k < kc * 8 + 8; ++k)
        s += d2[k] * D3[k * NOUTC + j3];
    red[t] = s;
    __syncthreads();
    if (t < NOUTC) {
      float v = c3[t];
#pragma unroll
      for (int i = 0; i < 64; ++i) v += red[i * 16 + t];
      out[b * NOUTC + t] = v;
    }
  }
}

// ---------------------------------------------------------------------------
extern "C" void kernel_launch(void* const* d_in, const int* in_sizes, int n_in,
                              void* d_out, int out_size, void* d_ws, size_t ws_size,
                              hipStream_t stream) {
  const float* x  = (const float*)d_in[0];
  const float* W1 = (const float*)d_in[1];
  const float* b1 = (const float*)d_in[2];
  const float* W2 = (const float*)d_in[3];
  const float* b2 = (const float*)d_in[4];
  const float* W3 = (const float*)d_in[5];
  const float* b3 = (const float*)d_in[6];
  const float* D1 = (const float*)d_in[7];
  const float* c1 = (const float*)d_in[8];
  const float* D2 = (const float*)d_in[9];
  const float* c2 = (const float*)d_in[10];
  const float* D3 = (const float*)d_in[11];
  const float* c3 = (const float*)d_in[12];

  // ws layout: [0,320K) packed bf16 W | [384K,416K) msum
  uint16_t* pW   = (uint16_t*)d_ws;
  float*    msum = (float*)((char*)d_ws + 384 * 1024);

  pack_weights<<<640, 256, 0, stream>>>(W1, W2, W3, pW, msum);
  encoder<<<NBLK, 256, 0, stream>>>(x, pW, b1, b2, b3, msum);
  decoder<<<BATCH, 1024, 0, stream>>>(msum, D1, c1, D2, c2, D3, c3,
                                      (float*)d_out);
}

// Round 11
// 176.287 us; speedup vs baseline: 1.2963x; 1.0005x over previous
//
#include <hip/hip_runtime.h>
#include <hip/hip_cooperative_groups.h>
#include <hip/hip_bf16.h>
#include <stdint.h>

namespace cg = cooperative_groups;

// ---------------------------------------------------------------------------
// TensorNet. R9's cooperative single-kernel never executed (output = zeros =
// launch-API failure, most likely hipErrorCooperativeLaunchTooLarge from the
// hardcoded grid = nb*256). R10 had a typo (this_grid;:()); R11 = R10 fixed:
// grid = occupancyAPI * mpCount attribute (the runtime's own validation
// arithmetic), launch return code CHECKED, fallback to the proven R8
// 3-kernel path (176us) on any coop failure. A static latch prevents
// re-issuing a failing coop launch during graph capture.
// ---------------------------------------------------------------------------

#define NIN   128
#define NHID  256
#define NDEC  512
#define NOUTC 10
#define BATCH 32
#define NTOK  4096
#define MTILE 64
#define NBLK  (BATCH * (NTOK / MTILE))   // 2048 encoder tiles
#define XPAD  136                         // x-tile LDS row stride (bf16)
#define HPAD  264                         // h-tile LDS row stride (bf16)

typedef short bf16x8 __attribute__((ext_vector_type(8)));
typedef float floatx4 __attribute__((ext_vector_type(4)));

__device__ __forceinline__ uint16_t f2b(float f) {
  union { uint32_t u; float f; } v; v.f = f;
  uint32_t r = v.u + 0x7FFFu + ((v.u >> 16) & 1u);   // RNE
  return (uint16_t)(r >> 16);
}
__device__ __forceinline__ uint32_t pkbf(float lo, float hi) {
  __hip_bfloat162 h = __float22bfloat162_rn(float2{lo, hi});  // v_cvt_pk_bf16_f32
  union { __hip_bfloat162 h; uint32_t u; } c; c.h = h;
  return c.u;
}

// ======================= shared device subroutines =========================
__device__ __forceinline__ void pack_one(
    int p, const float* __restrict__ W1, const float* __restrict__ W2,
    const float* __restrict__ W3, uint16_t* __restrict__ pW) {
  const float* W; int K; int base;
  if (p < 32768)      { W = W1; K = NIN;  base = 0; }
  else if (p < 98304) { W = W2; K = NHID; base = 32768; p -= 32768; }
  else                { W = W3; K = NHID; base = 98304; p -= 98304; }
  int j    = p & 7;
  int ln   = (p >> 3) & 63;
  int rest = p >> 9;
  int KC = K >> 5;
  int kc = rest % KC;
  int mt = rest / KC;
  int m = mt * 16 + (ln & 15);
  int k = kc * 32 + ((ln >> 4) << 3) + j;
  pW[base + (((mt * KC + kc) * 64 + ln) << 3) + j] = f2b(W[k * NHID + m]);
}

// Encoder tile body (R4/R7 structure, best measured). Hs = 33792 B LDS.
__device__ __forceinline__ void encoder_tile(
    int tile, int tid, uint16_t* Hs,
    const float* __restrict__ x, const uint16_t* __restrict__ pW,
    const float* __restrict__ b1, const float* __restrict__ b2,
    const float* __restrict__ b3, float* __restrict__ msum) {
  const int wave = tid >> 6;
  const int lane = tid & 63;
  const int l15  = lane & 15;
  const int q    = lane >> 4;
  const int tok0  = tile * MTILE;
  const int batch = tile >> 6;

  const uint16_t* pW1 = pW;             // KC=4
  const uint16_t* pW2 = pW + 32768;     // KC=8
  const uint16_t* pW3 = pW + 98304;     // KC=8

  // ---- stage x tile: fp32 -> bf16, rows stride XPAD ----
  {
    const int row = tid >> 2;
    const int c0  = (tid & 3) * 32;
    const float* xr = x + (size_t)(tok0 + row) * NIN + c0;
    for (int i = 0; i < 8; ++i) {
      float4 v = *(const float4*)(xr + i * 4);
      uint2 u = make_uint2(pkbf(v.x, v.y), pkbf(v.z, v.w));
      *(uint2*)&Hs[row * XPAD + c0 + i * 4] = u;
    }
  }
  __syncthreads();

  floatx4 acc[4][4];   // [jt][tt]

  // ---- layer 1: K = 128, A = W1^T, B = x ----
  for (int jt = 0; jt < 4; ++jt)
    for (int tt = 0; tt < 4; ++tt)
      acc[jt][tt] = (floatx4){0.f, 0.f, 0.f, 0.f};
#pragma unroll
  for (int kc = 0; kc < 4; ++kc) {
    bf16x8 a[4], b[4];
#pragma unroll
    for (int jt = 0; jt < 4; ++jt)
      a[jt] = *(const bf16x8*)(pW1 + ((((wave * 4 + jt) * 4 + kc) * 64 + lane) << 3));
#pragma unroll
    for (int tt = 0; tt < 4; ++tt)
      b[tt] = *(const bf16x8*)&Hs[(tt * 16 + l15) * XPAD + kc * 32 + q * 8];
#pragma unroll
    for (int jt = 0; jt < 4; ++jt)
#pragma unroll
      for (int tt = 0; tt < 4; ++tt)
        acc[jt][tt] = __builtin_amdgcn_mfma_f32_16x16x32_bf16(
            a[jt], b[tt], acc[jt][tt], 0, 0, 0);
  }
  __syncthreads();   // x reads done before h1 overwrites

#pragma unroll
  for (int jt = 0; jt < 4; ++jt) {
    const int jbase = wave * 64 + jt * 16 + q * 4;
    const float4 bb = *(const float4*)&b1[jbase];
#pragma unroll
    for (int tt = 0; tt < 4; ++tt) {
      const int t = tt * 16 + l15;
      float v0 = fmaxf(acc[jt][tt][0] + bb.x, 0.f);
      float v1 = fmaxf(acc[jt][tt][1] + bb.y, 0.f);
      float v2 = fmaxf(acc[jt][tt][2] + bb.z, 0.f);
      float v3 = fmaxf(acc[jt][tt][3] + bb.w, 0.f);
      *(uint2*)&Hs[t * HPAD + jbase] = make_uint2(pkbf(v0, v1), pkbf(v2, v3));
    }
  }
  __syncthreads();

  // ---- layer 2: K = 256, A = W2^T, B = h1 ----
  for (int jt = 0; jt < 4; ++jt)
    for (int tt = 0; tt < 4; ++tt)
      acc[jt][tt] = (floatx4){0.f, 0.f, 0.f, 0.f};
#pragma unroll
  for (int kc = 0; kc < 8; ++kc) {
    bf16x8 a[4], b[4];
#pragma unroll
    for (int jt = 0; jt < 4; ++jt)
      a[jt] = *(const bf16x8*)(pW2 + ((((wave * 4 + jt) * 8 + kc) * 64 + lane) << 3));
#pragma unroll
    for (int tt = 0; tt < 4; ++tt)
      b[tt] = *(const bf16x8*)&Hs[(tt * 16 + l15) * HPAD + kc * 32 + q * 8];
#pragma unroll
    for (int jt = 0; jt < 4; ++jt)
#pragma unroll
      for (int tt = 0; tt < 4; ++tt)
        acc[jt][tt] = __builtin_amdgcn_mfma_f32_16x16x32_bf16(
            a[jt], b[tt], acc[jt][tt], 0, 0, 0);
  }
  __syncthreads();   // h1 reads done before overwrite
#pragma unroll
  for (int jt = 0; jt < 4; ++jt) {
    const int jbase = wave * 64 + jt * 16 + q * 4;
    const float4 bb = *(const float4*)&b2[jbase];
#pragma unroll
    for (int tt = 0; tt < 4; ++tt) {
      const int t = tt * 16 + l15;
      float v0 = fmaxf(acc[jt][tt][0] + bb.x, 0.f);
      float v1 = fmaxf(acc[jt][tt][1] + bb.y, 0.f);
      float v2 = fmaxf(acc[jt][tt][2] + bb.z, 0.f);
      float v3 = fmaxf(acc[jt][tt][3] + bb.w, 0.f);
      *(uint2*)&Hs[t * HPAD + jbase] = make_uint2(pkbf(v0, v1), pkbf(v2, v3));
    }
  }
  __syncthreads();

  // ---- layer 3: K = 256, A = W3^T, B = h2, fused token-sum ----
  for (int jt = 0; jt < 4; ++jt)
    for (int tt = 0; tt < 4; ++tt)
      acc[jt][tt] = (floatx4){0.f, 0.f, 0.f, 0.f};
#pragma unroll
  for (int kc = 0; kc < 8; ++kc) {
    bf16x8 a[4], b[4];
#pragma unroll
    for (int jt = 0; jt < 4; ++jt)
      a[jt] = *(const bf16x8*)(pW3 + ((((wave * 4 + jt) * 8 + kc) * 64 + lane) << 3));
#pragma unroll
    for (int tt = 0; tt < 4; ++tt)
      b[tt] = *(const bf16x8*)&Hs[(tt * 16 + l15) * HPAD + kc * 32 + q * 8];
#pragma unroll
    for (int jt = 0; jt < 4; ++jt)
#pragma unroll
      for (int tt = 0; tt < 4; ++tt)
        acc[jt][tt] = __builtin_amdgcn_mfma_f32_16x16x32_bf16(
            a[jt], b[tt], acc[jt][tt], 0, 0, 0);
  }
  __syncthreads();   // h2 reads done before scratch overwrites Hs

  // scratch rows padded 17 float4: final-read bank = (4c+4l+r)%32, 2-way
  {
    float4* scratch = (float4*)Hs;
#pragma unroll
    for (int jt = 0; jt < 4; ++jt) {
      const int jbase = wave * 64 + jt * 16 + q * 4;
      const float4 bb = *(const float4*)&b3[jbase];
      float s0 = 0.f, s1 = 0.f, s2 = 0.f, s3 = 0.f;
#pragma unroll
      for (int tt = 0; tt < 4; ++tt) {
        s0 += fmaxf(acc[jt][tt][0] + bb.x, 0.f);
        s1 += fmaxf(acc[jt][tt][1] + bb.y, 0.f);
        s2 += fmaxf(acc[jt][tt][2] + bb.z, 0.f);
        s3 += fmaxf(acc[jt][tt][3] + bb.w, 0.f);
      }
      scratch[((wave * 4 + jt) * 4 + q) * 17 + l15] = (float4){s0, s1, s2, s3};
    }
  }
  __syncthreads();
  {
    const int c = tid >> 2;
    const int r = tid & 3;
    const float* sf = (const float*)Hs;
    float v = 0.f;
#pragma unroll
    for (int l = 0; l < 16; ++l)
      v += sf[c * 68 + l * 4 + r];
    const int wv = c >> 4, jt = (c >> 2) & 3, qq = c & 3;
    const int j = wv * 64 + jt * 16 + qq * 4 + r;
    atomicAdd(&msum[batch * NHID + j], v);
  }
}

// ============================ cooperative fused ============================
__global__ __launch_bounds__(256) void fused(
    const float* __restrict__ x,
    const float* __restrict__ W1, const float* __restrict__ b1,
    const float* __restrict__ W2, const float* __restrict__ b2,
    const float* __restrict__ W3, const float* __restrict__ b3,
    const float* __restrict__ D1, const float* __restrict__ c1,
    const float* __restrict__ D2, const float* __restrict__ c2,
    const float* __restrict__ D3, const float* __restrict__ c3,
    uint16_t* __restrict__ pW, float* __restrict__ msum,
    float* __restrict__ d1s, float* __restrict__ d2s,
    float* __restrict__ out) {
  cg::grid_group grid = cg::this_grid();
  __shared__ __align__(16) uint16_t Hs[MTILE * HPAD];

  const int tid = threadIdx.x;
  const int gstep = gridDim.x * 256;

  // phase 0: pack weights + zero msum
  for (int p0 = blockIdx.x * 256 + tid; p0 < 163840; p0 += gstep)
    pack_one(p0, W1, W2, W3, pW);
  for (int p0 = blockIdx.x * 256 + tid; p0 < BATCH * NHID; p0 += gstep)
    msum[p0] = 0.f;
  __threadfence();
  grid.sync();

  // phase 1: encoder over 2048 tiles
  for (int tile = blockIdx.x; tile < NBLK; tile += gridDim.x) {
    __syncthreads();
    encoder_tile(tile, tid, Hs, x, pW, b1, b2, b3, msum);
  }
  __threadfence();
  grid.sync();

  // phase 2: dec1 (256 block-slots)
  for (int blk = blockIdx.x; blk < 256; blk += gridDim.x) {
    const int b = blk >> 3, jc = blk & 7;
    float* p   = (float*)Hs;
    float* red = p + 256;
    __syncthreads();
    {
      float m = msum[b * NHID + tid] * (1.f / NTOK);
      p[tid] = m * m;
    }
    __syncthreads();
    const int j  = jc * 64 + (tid & 63);
    const int kc = tid >> 6;
    float s = 0.f;
    for (int k = kc * 64; k < kc * 64 + 64; ++k)
      s += p[k] * D1[k * NDEC + j];
    red[tid] = s;
    __syncthreads();
    if (tid < 64) {
      float v = red[tid] + red[64 + tid] + red[128 + tid] + red[192 + tid]
              + c1[jc * 64 + tid];
      d1s[b * NDEC + jc * 64 + tid] = fmaxf(v, 0.f);
    }
  }
  __threadfence();
  grid.sync();

  // phase 3: dec2
  for (int blk = blockIdx.x; blk < 256; blk += gridDim.x) {
    const int b = blk >> 3, jc = blk & 7;
    float* h   = (float*)Hs;
    float* red = h + NDEC;
    __syncthreads();
    h[tid]       = d1s[b * NDEC + tid];
    h[tid + 256] = d1s[b * NDEC + tid + 256];
    __syncthreads();
    const int j  = jc * 64 + (tid & 63);
    const int kc = tid >> 6;
    float s = 0.f;
    for (int k = kc * 128; k < kc * 128 + 128; ++k)
      s += h[k] * D2[k * NDEC + j];
    red[tid] = s;
    __syncthreads();
    if (tid < 64) {
      float v = red[tid] + red[64 + tid] + red[128 + tid] + red[192 + tid]
              + c2[jc * 64 + tid];
      d2s[b * NDEC + jc * 64 + tid] = fmaxf(v, 0.f);
    }
  }
  __threadfence();
  grid.sync();

  // phase 4: dec3
  for (int blk = blockIdx.x; blk < BATCH; blk += gridDim.x) {
    float* h   = (float*)Hs;
    float* red = h + NDEC;
    __syncthreads();
    h[tid]       = d2s[blk * NDEC + tid];
    h[tid + 256] = d2s[blk * NDEC + tid + 256];
    __syncthreads();
    const int j3 = tid & 15;
    const int kc = tid >> 4;
    float s = 0.f;
    if (j3 < NOUTC)
      for (int k = kc * 32; k < kc * 32 + 32; ++k)
        s += h[k] * D3[k * NOUTC + j3];
    red[tid] = s;
    __syncthreads();
    if (tid < NOUTC) {
      float v = c3[tid];
#pragma unroll
      for (int i = 0; i < 16; ++i) v += red[i * 16 + tid];
      out[blk * NOUTC + tid] = v;
    }
  }
}

// ====================== fallback kernels (R8, proven) ======================
__global__ __launch_bounds__(256) void pack_weights(
    const float* __restrict__ W1, const float* __restrict__ W2,
    const float* __restrict__ W3, uint16_t* __restrict__ pW,
    float* __restrict__ msum) {
  int p = blockIdx.x * blockDim.x + threadIdx.x;
  if (p < BATCH * NHID) msum[p] = 0.f;
  pack_one(p, W1, W2, W3, pW);
}

__global__ __launch_bounds__(256) void encoder(
    const float* __restrict__ x, const uint16_t* __restrict__ pW,
    const float* __restrict__ b1, const float* __restrict__ b2,
    const float* __restrict__ b3, float* __restrict__ msum) {
  __shared__ __align__(16) uint16_t Hs[MTILE * HPAD];
  encoder_tile(blockIdx.x, threadIdx.x, Hs, x, pW, b1, b2, b3, msum);
}

__global__ __launch_bounds__(1024) void decoder(
    const float* __restrict__ msum,
    const float* __restrict__ D1, const float* __restrict__ c1,
    const float* __restrict__ D2, const float* __restrict__ c2,
    const float* __restrict__ D3, const float* __restrict__ c3,
    float* __restrict__ out) {
  __shared__ float p[NHID];
  __shared__ float d1[NDEC];
  __shared__ float d2[NDEC];
  __shared__ float red[1024];
  const int b = blockIdx.x, t = threadIdx.x;

  if (t < NHID) {
    float m = msum[b * NHID + t] * (1.f / NTOK);
    p[t] = m * m;
  }
  __syncthreads();

  const int j = t & 511;
  const int h = t >> 9;

  {
    float s = 0.f;
    for (int k = h * 128; k < h * 128 + 128; ++k)
      s += p[k] * D1[k * NDEC + j];
    red[t] = s;
    __syncthreads();
    if (t < NDEC)
      d1[t] = fmaxf(red[t] + red[512 + t] + c1[t], 0.f);
    __syncthreads();
  }
  {
    float s = 0.f;
    for (int k = h * 256; k < h * 256 + 256; ++k)
      s += d1[k] * D2[k * NDEC + j];
    red[t] = s;
    __syncthreads();
    if (t < NDEC)
      d2[t] = fmaxf(red[t] + red[512 + t] + c2[t], 0.f);
    __syncthreads();
  }
  {
    const int j3 = t & 15;
    const int kc = t >> 4;
    float s = 0.f;
    if (j3 < NOUTC)
      for (int k = kc * 8; k < kc * 8 + 8; ++k)
        s += d2[k] * D3[k * NOUTC + j3];
    red[t] = s;
    __syncthreads();
    if (t < NOUTC) {
      float v = c3[t];
#pragma unroll
      for (int i = 0; i < 64; ++i) v += red[i * 16 + t];
      out[b * NOUTC + t] = v;
    }
  }
}

// ---------------------------------------------------------------------------
static int g_coop_failed = 0;   // latch: never re-issue a failing coop launch
                                // (keeps graph capture clean; work identical)

extern "C" void kernel_launch(void* const* d_in, const int* in_sizes, int n_in,
                              void* d_out, int out_size, void* d_ws, size_t ws_size,
                              hipStream_t stream) {
  const float* x  = (const float*)d_in[0];
  const float* W1 = (const float*)d_in[1];
  const float* b1 = (const float*)d_in[2];
  const float* W2 = (const float*)d_in[3];
  const float* b2 = (const float*)d_in[4];
  const float* W3 = (const float*)d_in[5];
  const float* b3 = (const float*)d_in[6];
  const float* D1 = (const float*)d_in[7];
  const float* c1 = (const float*)d_in[8];
  const float* D2 = (const float*)d_in[9];
  const float* c2 = (const float*)d_in[10];
  const float* D3 = (const float*)d_in[11];
  const float* c3 = (const float*)d_in[12];

  uint16_t* pW   = (uint16_t*)d_ws;
  float*    msum = (float*)((char*)d_ws + 384 * 1024);
  float*    d1s  = (float*)((char*)d_ws + 448 * 1024);
  float*    d2s  = (float*)((char*)d_ws + 512 * 1024);
  float*    out  = (float*)d_out;

  if (!g_coop_failed) {
    // Capacity per the runtime's own arithmetic: occupancy API x mpCount.
    int dev = 0;
    (void)hipGetDevice(&dev);
    int mp = 0;
    if (hipDeviceGetAttribute(&mp, hipDeviceAttributeMultiprocessorCount,
                              dev) != hipSuccess || mp <= 0)
      mp = 256;
    int nb = 0;
    if (hipOccupancyMaxActiveBlocksPerMultiprocessor(
            &nb, (const void*)fused, 256, 0) != hipSuccess || nb < 1)
      nb = 1;   // ultra-conservative: 1 block/CU always co-resident
    long grid = (long)nb * (long)mp;
    if (grid > NBLK) grid = NBLK;
    if (grid < 1) grid = 1;

    void* args[] = {
        (void*)&x,  (void*)&W1, (void*)&b1, (void*)&W2, (void*)&b2,
        (void*)&W3, (void*)&b3, (void*)&D1, (void*)&c1, (void*)&D2,
        (void*)&c2, (void*)&D3, (void*)&c3, (void*)&pW, (void*)&msum,
        (void*)&d1s, (void*)&d2s, (void*)&out};
    hipError_t e = hipLaunchCooperativeKernel(
        (const void*)fused, dim3((unsigned)grid), dim3(256), args, 0, stream);
    if (e == hipSuccess) return;
    g_coop_failed = 1;   // fall through to the proven 3-kernel path
  }

  pack_weights<<<640, 256, 0, stream>>>(W1, W2, W3, pW, msum);
  encoder<<<NBLK, 256, 0, stream>>>(x, pW, b1, b2, b3, msum);
  decoder<<<BATCH, 1024, 0, stream>>>(msum, D1, c1, D2, c2, D3, c3, out);
}

// Round 12
// 173.363 us; speedup vs baseline: 1.3182x; 1.0169x over previous
//
#include <hip/hip_runtime.h>
#include <hip/hip_bf16.h>
#include <stdint.h>

// ---------------------------------------------------------------------------
// TensorNet: fused encoder MLP (128->256->256->256, relu) over 32x4096 tokens,
// per-batch mean -> p = relu(m^2) -> decoder MLP (256->512->512->10).
// Inputs/outputs fp32. Encoder via bf16 MFMA (A=weights M=hidden, B=act
// N=tokens) + fp32 accum.
// R11 verdict: cooperative single-kernel launches but (a) VGPR 92->176 kills
// occupancy (378us vs 176us) and (b) coop launch FAILS under graph capture,
// so the timed path can never use it. Coop removed. 3 nodes is the floor
// (pack->encoder->decoder hard deps; dispatch-order spin barriers forbidden).
// R12: decoder inner loops vectorized 4-wide over j (float4 D reads,
// coalesced) with 8-way K-split -> 32/64 iter vs 128/256 scalar.
// ---------------------------------------------------------------------------

#define NIN   128
#define NHID  256
#define NDEC  512
#define NOUTC 10
#define BATCH 32
#define NTOK  4096
#define MTILE 64
#define NBLK  (BATCH * (NTOK / MTILE))   // 2048 encoder tiles
#define XPAD  136                         // x-tile LDS row stride (bf16)
#define HPAD  264                         // h-tile LDS row stride (bf16)

typedef short bf16x8 __attribute__((ext_vector_type(8)));
typedef float floatx4 __attribute__((ext_vector_type(4)));

__device__ __forceinline__ uint16_t f2b(float f) {
  union { uint32_t u; float f; } v; v.f = f;
  uint32_t r = v.u + 0x7FFFu + ((v.u >> 16) & 1u);   // RNE
  return (uint16_t)(r >> 16);
}
__device__ __forceinline__ uint32_t pkbf(float lo, float hi) {
  __hip_bfloat162 h = __float22bfloat162_rn(float2{lo, hi});  // v_cvt_pk_bf16_f32
  union { __hip_bfloat162 h; uint32_t u; } c; c.h = h;
  return c.u;
}

// ---------------------------------------------------------------------------
// Pack W1/W2/W3 (fp32 [K][256] row-major) into bf16 MFMA-A-fragment order.
// Also zero-inits msum (poisoned 0xAA by the harness).
// ---------------------------------------------------------------------------
__global__ __launch_bounds__(256) void pack_weights(
    const float* __restrict__ W1, const float* __restrict__ W2,
    const float* __restrict__ W3, uint16_t* __restrict__ pW,
    float* __restrict__ msum) {
  int p = blockIdx.x * blockDim.x + threadIdx.x;
  if (p < BATCH * NHID) msum[p] = 0.f;
  const float* W; int K; int base;
  if (p < 32768)      { W = W1; K = NIN;  base = 0; }
  else if (p < 98304) { W = W2; K = NHID; base = 32768; p -= 32768; }
  else                { W = W3; K = NHID; base = 98304; p -= 98304; }
  int j    = p & 7;
  int ln   = (p >> 3) & 63;
  int rest = p >> 9;
  int KC = K >> 5;
  int kc = rest % KC;
  int mt = rest / KC;
  int m = mt * 16 + (ln & 15);
  int k = kc * 32 + ((ln >> 4) << 3) + j;
  pW[base + (((mt * KC + kc) * 64 + ln) << 3) + j] = f2b(W[k * NHID + m]);
}

// ---------------------------------------------------------------------------
// Fused encoder (R4/R7 structure, best measured ~66us). Block = 256 thr
// (4 waves), 64 tokens. Wave w owns hidden rows [64w,64w+64) (A = packed
// weights); token tiles shared (B from LDS). D: lane holds j = jbase+r run.
// NOTE: plain __launch_bounds__(256) — (256,4) forces VGPR=64 and spills
// the 64-VGPR accumulator (R5: +20MB HBM writes).
// ---------------------------------------------------------------------------
__global__ __launch_bounds__(256) void encoder(
    const float* __restrict__ x,        // [BATCH*NTOK][NIN] fp32
    const uint16_t* __restrict__ pW,
    const float* __restrict__ b1,
    const float* __restrict__ b2,
    const float* __restrict__ b3,
    float* __restrict__ msum) {         // [BATCH][NHID] fp32 accum
  __shared__ __align__(16) uint16_t Hs[MTILE * HPAD];  // 33792 B

  const int tid  = threadIdx.x;
  const int wave = tid >> 6;
  const int lane = tid & 63;
  const int l15  = lane & 15;
  const int q    = lane >> 4;
  const int tok0  = blockIdx.x * MTILE;
  const int batch = blockIdx.x >> 6;

  const uint16_t* pW1 = pW;             // KC=4
  const uint16_t* pW2 = pW + 32768;     // KC=8
  const uint16_t* pW3 = pW + 98304;     // KC=8

  // ---- stage x tile: fp32 -> bf16, rows stride XPAD ----
  {
    const int row = tid >> 2;
    const int c0  = (tid & 3) * 32;
    const float* xr = x + (size_t)(tok0 + row) * NIN + c0;
    for (int i = 0; i < 8; ++i) {
      float4 v = *(const float4*)(xr + i * 4);
      uint2 u = make_uint2(pkbf(v.x, v.y), pkbf(v.z, v.w));
      *(uint2*)&Hs[row * XPAD + c0 + i * 4] = u;
    }
  }
  __syncthreads();

  floatx4 acc[4][4];   // [jt][tt]

  // ---- layer 1: K = 128, A = W1^T, B = x ----
  for (int jt = 0; jt < 4; ++jt)
    for (int tt = 0; tt < 4; ++tt)
      acc[jt][tt] = (floatx4){0.f, 0.f, 0.f, 0.f};
#pragma unroll
  for (int kc = 0; kc < 4; ++kc) {
    bf16x8 a[4], b[4];
#pragma unroll
    for (int jt = 0; jt < 4; ++jt)
      a[jt] = *(const bf16x8*)(pW1 + ((((wave * 4 + jt) * 4 + kc) * 64 + lane) << 3));
#pragma unroll
    for (int tt = 0; tt < 4; ++tt)
      b[tt] = *(const bf16x8*)&Hs[(tt * 16 + l15) * XPAD + kc * 32 + q * 8];
#pragma unroll
    for (int jt = 0; jt < 4; ++jt)
#pragma unroll
      for (int tt = 0; tt < 4; ++tt)
        acc[jt][tt] = __builtin_amdgcn_mfma_f32_16x16x32_bf16(
            a[jt], b[tt], acc[jt][tt], 0, 0, 0);
  }
  __syncthreads();   // x reads done before h1 overwrites

#pragma unroll
  for (int jt = 0; jt < 4; ++jt) {
    const int jbase = wave * 64 + jt * 16 + q * 4;
    const float4 bb = *(const float4*)&b1[jbase];
#pragma unroll
    for (int tt = 0; tt < 4; ++tt) {
      const int t = tt * 16 + l15;
      float v0 = fmaxf(acc[jt][tt][0] + bb.x, 0.f);
      float v1 = fmaxf(acc[jt][tt][1] + bb.y, 0.f);
      float v2 = fmaxf(acc[jt][tt][2] + bb.z, 0.f);
      float v3 = fmaxf(acc[jt][tt][3] + bb.w, 0.f);
      *(uint2*)&Hs[t * HPAD + jbase] = make_uint2(pkbf(v0, v1), pkbf(v2, v3));
    }
  }
  __syncthreads();

  // ---- layer 2: K = 256, A = W2^T, B = h1 ----
  for (int jt = 0; jt < 4; ++jt)
    for (int tt = 0; tt < 4; ++tt)
      acc[jt][tt] = (floatx4){0.f, 0.f, 0.f, 0.f};
#pragma unroll
  for (int kc = 0; kc < 8; ++kc) {
    bf16x8 a[4], b[4];
#pragma unroll
    for (int jt = 0; jt < 4; ++jt)
      a[jt] = *(const bf16x8*)(pW2 + ((((wave * 4 + jt) * 8 + kc) * 64 + lane) << 3));
#pragma unroll
    for (int tt = 0; tt < 4; ++tt)
      b[tt] = *(const bf16x8*)&Hs[(tt * 16 + l15) * HPAD + kc * 32 + q * 8];
#pragma unroll
    for (int jt = 0; jt < 4; ++jt)
#pragma unroll
      for (int tt = 0; tt < 4; ++tt)
        acc[jt][tt] = __builtin_amdgcn_mfma_f32_16x16x32_bf16(
            a[jt], b[tt], acc[jt][tt], 0, 0, 0);
  }
  __syncthreads();   // h1 reads done before overwrite
#pragma unroll
  for (int jt = 0; jt < 4; ++jt) {
    const int jbase = wave * 64 + jt * 16 + q * 4;
    const float4 bb = *(const float4*)&b2[jbase];
#pragma unroll
    for (int tt = 0; tt < 4; ++tt) {
      const int t = tt * 16 + l15;
      float v0 = fmaxf(acc[jt][tt][0] + bb.x, 0.f);
      float v1 = fmaxf(acc[jt][tt][1] + bb.y, 0.f);
      float v2 = fmaxf(acc[jt][tt][2] + bb.z, 0.f);
      float v3 = fmaxf(acc[jt][tt][3] + bb.w, 0.f);
      *(uint2*)&Hs[t * HPAD + jbase] = make_uint2(pkbf(v0, v1), pkbf(v2, v3));
    }
  }
  __syncthreads();

  // ---- layer 3: K = 256, A = W3^T, B = h2, fused token-sum ----
  for (int jt = 0; jt < 4; ++jt)
    for (int tt = 0; tt < 4; ++tt)
      acc[jt][tt] = (floatx4){0.f, 0.f, 0.f, 0.f};
#pragma unroll
  for (int kc = 0; kc < 8; ++kc) {
    bf16x8 a[4], b[4];
#pragma unroll
    for (int jt = 0; jt < 4; ++jt)
      a[jt] = *(const bf16x8*)(pW3 + ((((wave * 4 + jt) * 8 + kc) * 64 + lane) << 3));
#pragma unroll
    for (int tt = 0; tt < 4; ++tt)
      b[tt] = *(const bf16x8*)&Hs[(tt * 16 + l15) * HPAD + kc * 32 + q * 8];
#pragma unroll
    for (int jt = 0; jt < 4; ++jt)
#pragma unroll
      for (int tt = 0; tt < 4; ++tt)
        acc[jt][tt] = __builtin_amdgcn_mfma_f32_16x16x32_bf16(
            a[jt], b[tt], acc[jt][tt], 0, 0, 0);
  }
  __syncthreads();   // h2 reads done before scratch overwrites Hs

  // bias + relu + partial token-sum; scratch rows padded 17 float4 so the
  // final read's bank = (4c+4l+r)%32 (2-way, free) not (4l+r)%32 (16-way).
  {
    float4* scratch = (float4*)Hs;
#pragma unroll
    for (int jt = 0; jt < 4; ++jt) {
      const int jbase = wave * 64 + jt * 16 + q * 4;
      const float4 bb = *(const float4*)&b3[jbase];
      float s0 = 0.f, s1 = 0.f, s2 = 0.f, s3 = 0.f;
#pragma unroll
      for (int tt = 0; tt < 4; ++tt) {
        s0 += fmaxf(acc[jt][tt][0] + bb.x, 0.f);
        s1 += fmaxf(acc[jt][tt][1] + bb.y, 0.f);
        s2 += fmaxf(acc[jt][tt][2] + bb.z, 0.f);
        s3 += fmaxf(acc[jt][tt][3] + bb.w, 0.f);
      }
      scratch[((wave * 4 + jt) * 4 + q) * 17 + l15] = (float4){s0, s1, s2, s3};
    }
  }
  __syncthreads();
  {
    const int c = tid >> 2;
    const int r = tid & 3;
    const float* sf = (const float*)Hs;
    float v = 0.f;
#pragma unroll
    for (int l = 0; l < 16; ++l)
      v += sf[c * 68 + l * 4 + r];
    const int wv = c >> 4, jt = (c >> 2) & 3, qq = c & 3;
    const int j = wv * 64 + jt * 16 + qq * 4 + r;
    atomicAdd(&msum[batch * NHID + j], v);
  }
}

// ---------------------------------------------------------------------------
// Decoder: one block per batch, 1024 threads. R12: 4-wide j-vectorization
// (float4 reads of D1/D2, coalesced across threads) + 8-way K-split ->
// per-thread loops 32 (L1) / 64 (L2) iterations vs 128/256 scalar before.
// red layout: red[ks*512 + j] (float4 write at t*4) -> reduction read
// red[i*512+t] is conflict-free (consecutive t = consecutive banks).
// ---------------------------------------------------------------------------
__global__ __launch_bounds__(1024) void decoder(
    const float* __restrict__ msum,
    const float* __restrict__ D1, const float* __restrict__ c1,
    const float* __restrict__ D2, const float* __restrict__ c2,
    const float* __restrict__ D3, const float* __restrict__ c3,
    float* __restrict__ out) {
  __shared__ float p[NHID];
  __shared__ float d1[NDEC];
  __shared__ float d2[NDEC];
  __shared__ __align__(16) float red[4096];   // 16 KB
  const int b = blockIdx.x, t = threadIdx.x;

  if (t < NHID) {
    float m = msum[b * NHID + t] * (1.f / NTOK);
    p[t] = m * m;                        // relu(m^2) == m^2
  }
  __syncthreads();

  const int jg = t & 127;                // j-group of 4 (j = jg*4 .. jg*4+3)
  const int ks = t >> 7;                 // 0..7 K-split

  // ---- layer 1: K = 256 -> 32 k per split ----
  {
    const float4* D1v = (const float4*)D1;   // [256][128] float4
    float4 s = {0.f, 0.f, 0.f, 0.f};
    for (int k = ks * 32; k < ks * 32 + 32; ++k) {
      float4 w = D1v[k * 128 + jg];
      float pv = p[k];
      s.x += pv * w.x; s.y += pv * w.y; s.z += pv * w.z; s.w += pv * w.w;
    }
    *(float4*)&red[t * 4] = s;           // red[ks*512 + jg*4 + c]
    __syncthreads();
    if (t < NDEC) {
      float v = c1[t];
#pragma unroll
      for (int i = 0; i < 8; ++i) v += red[i * 512 + t];
      d1[t] = fmaxf(v, 0.f);
    }
    __syncthreads();
  }

  // ---- layer 2: K = 512 -> 64 k per split ----
  {
    const float4* D2v = (const float4*)D2;   // [512][128] float4
    float4 s = {0.f, 0.f, 0.f, 0.f};
    for (int k = ks * 64; k < ks * 64 + 64; ++k) {
      float4 w = D2v[k * 128 + jg];
      float hv = d1[k];
      s.x += hv * w.x; s.y += hv * w.y; s.z += hv * w.z; s.w += hv * w.w;
    }
    *(float4*)&red[t * 4] = s;
    __syncthreads();
    if (t < NDEC) {
      float v = c2[t];
#pragma unroll
      for (int i = 0; i < 8; ++i) v += red[i * 512 + t];
      d2[t] = fmaxf(v, 0.f);
    }
    __syncthreads();
  }

  // ---- layer 3: [512][10]; 64 k-chunks x 16 j-slots (10 valid) ----
  {
    const int j3 = t & 15;
    const int kc = t >> 4;               // 0..63, 8 k's each
    float s = 0.f;
    if (j3 < NOUTC)
      for (int k = kc * 8; k < kc * 8 + 8; ++k)
        s += d2[k] * D3[k * NOUTC + j3];
    red[t] = s;
    __syncthreads();
    if (t < NOUTC) {
      float v = c3[t];
#pragma unroll
      for (int i = 0; i < 64; ++i) v += red[i * 16 + t];
      out[b * NOUTC + t] = v;
    }
  }
}

// ---------------------------------------------------------------------------
extern "C" void kernel_launch(void* const* d_in, const int* in_sizes, int n_in,
                              void* d_out, int out_size, void* d_ws, size_t ws_size,
                              hipStream_t stream) {
  const float* x  = (const float*)d_in[0];
  const float* W1 = (const float*)d_in[1];
  const float* b1 = (const float*)d_in[2];
  const float* W2 = (const float*)d_in[3];
  const float* b2 = (const float*)d_in[4];
  const float* W3 = (const float*)d_in[5];
  const float* b3 = (const float*)d_in[6];
  const float* D1 = (const float*)d_in[7];
  const float* c1 = (const float*)d_in[8];
  const float* D2 = (const float*)d_in[9];
  const float* c2 = (const float*)d_in[10];
  const float* D3 = (const float*)d_in[11];
  const float* c3 = (const float*)d_in[12];

  // ws: [0,320K) packed bf16 W | [384K,416K) msum
  uint16_t* pW   = (uint16_t*)d_ws;
  float*    msum = (float*)((char*)d_ws + 384 * 1024);

  pack_weights<<<640, 256, 0, stream>>>(W1, W2, W3, pW, msum);
  encoder<<<NBLK, 256, 0, stream>>>(x, pW, b1, b2, b3, msum);
  decoder<<<BATCH, 1024, 0, stream>>>(msum, D1, c1, D2, c2, D3, c3,
                                      (float*)d_out);
}